// Round 3
// baseline (697.471 us; speedup 1.0000x reference)
//
#include <hip/hip_runtime.h>
#include <hip/hip_bf16.h>

// MapAgent: NatureCNN (3 convs + FC) -> map-write scan -> policy/value heads.
// T=32, B=64, TB=2048.
//
// R10 change (theory: R9's one-barrier conv1 still 112us with ALL pipes idle
// (Mfma 4.7%, VALU 11%, HBM 19%, occ 40%): 40KB LDS caps residency at
// 4 blocks/CU and the load->cvt->LDS->barrier->MFMA chain serializes.
// MFMA A/B fragments are per-lane PRIVATE data -- LDS provides nothing):
//  * conv1/conv2/conv3: delete LDS + barriers entirely. Each lane loads its
//    own A-fragment directly from global/L1 (dwordx4, many in flight),
//    B-fragments per-tap from L1-resident prepped weights. Blocks = 4
//    independent waves; occupancy VGPR-bound; latency hidden by ILP x TLP.
//  * Epilogues/layouts/all other kernels unchanged (bit-identical math).

#define TT 32
#define BB 64
#define TBR 2048

typedef _Float16 half_t;
typedef __attribute__((ext_vector_type(8))) _Float16 half8;
typedef __attribute__((ext_vector_type(4))) float f32x4;

// ---- workspace offsets (floats) ----
#define OFF_W1T   0u          // 4096    : w1p fp16 [tap8][oc32][k32] zero-pad
#define OFF_W2T   6144u       // 16384   : w2T fp16 [tap16][oc64][c32]
#define OFF_W3T   22528u      // 18432   : w3T fp16 [tap9][oc64][c64]
#define OFF_WF    40960u      // 65536   : wfeat [2048][32]
#define OFF_PF    106496u     // 131072  : posfeat [2048][64]
#define OFF_Y0    237568u     // 8192    : y0 [64][128]
#define OFF_YS    245760u     // 262144  : ystate [2048][128]
#define OFF_H     507904u     // 1048576 : h [2048][512]
#define OFF_WFCT  1556480u    // 802816  : wfcT fp16 [512][3136] (k=c*49+pos)
#define OFF_C3    2359296u    // 3211264 : c3b fp16 [2048][3136]
#define OFF_C2    5570560u    // 5308416 : c2b fp16 [2048][9][9][64]
#define OFF_C1    10878976u   // c1b fp16 [CS][20][20][32]

// ---------------- weight prep ----------------
__global__ __launch_bounds__(256) void prep_kernel(
    const float* __restrict__ w1, const float* __restrict__ w2,
    const float* __restrict__ w3, half_t* __restrict__ w1p,
    half_t* __restrict__ w2T, half_t* __restrict__ w3T) {
  int g = blockIdx.x * 256 + threadIdx.x;   // 77824 total
  if (g < 8192) {
    // w1p[(tap*32+oc)*32+kk], kk = kx*3+c (<24) else 0 ; w1 is [oc][c][ky*8+kx]
    int kk = g & 31, oc = (g >> 5) & 31, tap = g >> 10;
    half_t v = (half_t)0.f;
    if (kk < 24) {
      int kx = kk / 3, c = kk - 3 * kx;
      v = (half_t)(w1[oc * 192 + c * 64 + tap * 8 + kx] * (1.0f / 255.0f));
    }
    w1p[g] = v;
    return;
  }
  int g2 = g - 8192;
  if (g2 < 32768) {                          // w2T[(tap*64+oc)*32+c]
    int c = g2 & 31, oc = (g2 >> 5) & 63, tap = g2 >> 11;
    w2T[g2] = (half_t)w2[oc * 512 + c * 16 + tap];
    return;
  }
  int g3 = g2 - 32768;
  if (g3 < 36864) {                          // w3T[(tap*64+oc)*64+c]
    int c = g3 & 63, oc = (g3 >> 6) & 63, tap = g3 >> 12;
    w3T[g3] = (half_t)w3[oc * 576 + c * 9 + tap];
  }
}

// ---- wfcT[n][k] = (half)wfc[k][n], k = c*49+pos : LDS-tiled transpose ----
__global__ __launch_bounds__(256) void prep_wfct(
    const float* __restrict__ wfc, half_t* __restrict__ wfcT) {
  __shared__ float t[32][33];
  int k0 = blockIdx.x * 32, n0 = blockIdx.y * 32;
  int tx = threadIdx.x & 31, ty = threadIdx.x >> 5;  // ty 0..7
#pragma unroll
  for (int i = 0; i < 4; ++i)
    t[ty + 8 * i][tx] = wfc[(size_t)(k0 + ty + 8 * i) * 512 + n0 + tx];
  __syncthreads();
#pragma unroll
  for (int i = 0; i < 4; ++i)
    wfcT[(size_t)(n0 + ty + 8 * i) * 3136 + k0 + tx] =
        (half_t)t[tx][ty + 8 * i];
}

// ---------------- conv1 MFMA, barrier-free: NHWC fp32 -> fp16 [li][20][20][32]
// One wave = 16 rows x 32 oc. Lane (lc,q) IS A-fragment row lc, k-seg q:
// loads its own 8 floats (2x dwordx4) per tap, cvt in-register. q==3 = K-pad
// (zero, weights also zero). B per-tap from 16KB L1-resident w1p.
__global__ __launch_bounds__(256) void conv1_mfma(
    const float* __restrict__ img, const half_t* __restrict__ w1p,
    const float* __restrict__ b1, half_t* __restrict__ out, int n0) {
  int tid = threadIdx.x;
  int m0 = blockIdx.x * 64;
  int w = tid >> 6, l = tid & 63, lc = l & 15, q = l >> 4;
  int ar = m0 + w * 16 + lc;                 // this lane's A row
  int li = ar / 400, pos = ar - li * 400;
  int oy = pos / 20, ox = pos - oy * 20;
  // float offset: (4oy+tap)*252 + 12*ox + 8*q -> mult of 4 -> 16B aligned
  const float* aBase =
      img + (size_t)(n0 + li) * 21168 + (4 * oy) * 252 + ox * 12 + q * 8;

  f32x4 fr[8][2];
  if (q < 3) {
#pragma unroll
    for (int tap = 0; tap < 8; ++tap) {      // 16 dwordx4 in flight
      const f32x4* p = (const f32x4*)(aBase + tap * 252);
      fr[tap][0] = p[0];
      fr[tap][1] = p[1];
    }
  }
  const half_t* bB = w1p + lc * 32 + q * 8;  // + tap*1024 + t*512

  f32x4 acc[2];
  acc[0] = (f32x4){0.f, 0.f, 0.f, 0.f};
  acc[1] = (f32x4){0.f, 0.f, 0.f, 0.f};
#pragma unroll
  for (int tap = 0; tap < 8; ++tap) {
    half8 af;
    if (q < 3) {
#pragma unroll
      for (int j = 0; j < 4; ++j) {
        af[j] = (half_t)fr[tap][0][j];
        af[4 + j] = (half_t)fr[tap][1][j];
      }
    } else {
#pragma unroll
      for (int j = 0; j < 8; ++j) af[j] = (half_t)0.f;
    }
    half8 bf0 = *(const half8*)(bB + tap * 1024);
    half8 bf1 = *(const half8*)(bB + tap * 1024 + 512);
    acc[0] = __builtin_amdgcn_mfma_f32_16x16x32_f16(af, bf0, acc[0], 0, 0, 0);
    acc[1] = __builtin_amdgcn_mfma_f32_16x16x32_f16(af, bf1, acc[1], 0, 0, 0);
  }
  // C: row=w*16+q*4+r, col=t*16+lc [m89]; out layout [m][32] channels-last
#pragma unroll
  for (int t = 0; t < 2; ++t) {
#pragma unroll
    for (int r = 0; r < 4; ++r) {
      int mr = m0 + w * 16 + q * 4 + r;
      int col = t * 16 + lc;
      out[(size_t)mr * 32 + col] = (half_t)fmaxf(acc[t][r] + b1[col], 0.f);
    }
  }
}

// ---------------- conv2 MFMA, barrier-free: -> fp16 [li][9][9][64] ----------
// Lane (lc,q) loads its own A-fragment (16B) per tap from L1/L2-hot c1b;
// B per-tap from w2T. 16 taps in two 8-deep load groups.
__global__ __launch_bounds__(256) void conv2_mfma(
    const half_t* __restrict__ in, const half_t* __restrict__ w2T,
    const float* __restrict__ b2, half_t* __restrict__ out) {
  int tid = threadIdx.x;
  int m0 = blockIdx.x * 64;
  int w = tid >> 6, l = tid & 63, lc = l & 15, q = l >> 4;
  int ar = m0 + w * 16 + lc;
  int li = ar / 81, pos = ar - li * 81;
  int oy = pos / 9, ox = pos - oy * 9;
  const half_t* aRow =
      in + (size_t)((li * 20 + 2 * oy) * 20 + 2 * ox) * 32 + q * 8;
  const half_t* bB = w2T + lc * 32 + q * 8;  // + tap*2048 + t*512

  f32x4 acc[4];
#pragma unroll
  for (int t = 0; t < 4; ++t) acc[t] = (f32x4){0.f, 0.f, 0.f, 0.f};
#pragma unroll
  for (int hp = 0; hp < 2; ++hp) {
    uint4 a[8];
#pragma unroll
    for (int i = 0; i < 8; ++i) {            // 8 loads in flight
      int tap = hp * 8 + i, ky = tap >> 2, kx = tap & 3;
      a[i] = *(const uint4*)(aRow + (ky * 20 + kx) * 32);
    }
#pragma unroll
    for (int i = 0; i < 8; ++i) {
      int tap = hp * 8 + i;
      half8 af = *(half8*)&a[i];
#pragma unroll
      for (int t = 0; t < 4; ++t) {
        half8 bf = *(const half8*)(bB + tap * 2048 + t * 512);
        acc[t] = __builtin_amdgcn_mfma_f32_16x16x32_f16(af, bf, acc[t], 0, 0, 0);
      }
    }
  }
  // C: row=w*16+q*4+r, col=t*16+lc [m89]; out offset = m*64+col (layout [m][c])
#pragma unroll
  for (int t = 0; t < 4; ++t) {
#pragma unroll
    for (int r = 0; r < 4; ++r) {
      int mr = m0 + w * 16 + q * 4 + r;
      int col = t * 16 + lc;
      out[(size_t)mr * 64 + col] = (half_t)fmaxf(acc[t][r] + b2[col], 0.f);
    }
  }
}

// ---------------- conv3 MFMA, barrier-free: -> fp16 [li][c*49+pos] ----------
// 9 taps x 2 K-chunks; lane loads its own 16B A-fragment per (tap,ch).
__global__ __launch_bounds__(256) void conv3_mfma(
    const half_t* __restrict__ in, const half_t* __restrict__ w3T,
    const float* __restrict__ b3, half_t* __restrict__ out) {
  int tid = threadIdx.x;
  int m0 = blockIdx.x * 64;
  int w = tid >> 6, l = tid & 63, lc = l & 15, q = l >> 4;
  int ar = m0 + w * 16 + lc;
  int li = ar / 49, pos = ar - li * 49;
  int oy = pos / 7, ox = pos - oy * 7;
  const half_t* aRow = in + (size_t)((li * 9 + oy) * 9 + ox) * 64 + q * 8;
  const half_t* bB = w3T + lc * 64 + q * 8;  // + tap*4096 + ch*32 + t*1024

  f32x4 acc[4];
#pragma unroll
  for (int t = 0; t < 4; ++t) acc[t] = (f32x4){0.f, 0.f, 0.f, 0.f};
#pragma unroll
  for (int ch = 0; ch < 2; ++ch) {
    uint4 a[9];
#pragma unroll
    for (int tap = 0; tap < 9; ++tap) {      // 9 loads in flight
      int ky = tap / 3, kx = tap - ky * 3;
      a[tap] = *(const uint4*)(aRow + (ky * 9 + kx) * 64 + ch * 32);
    }
#pragma unroll
    for (int tap = 0; tap < 9; ++tap) {
      half8 af = *(half8*)&a[tap];
#pragma unroll
      for (int t = 0; t < 4; ++t) {
        half8 bf = *(const half8*)(bB + tap * 4096 + ch * 32 + t * 1024);
        acc[t] = __builtin_amdgcn_mfma_f32_16x16x32_f16(af, bf, acc[t], 0, 0, 0);
      }
    }
  }
  // write k-order c*49+pos (fc_mfma consumes this order; wfcT unchanged)
#pragma unroll
  for (int t = 0; t < 4; ++t) {
#pragma unroll
    for (int r = 0; r < 4; ++r) {
      int mr = m0 + w * 16 + q * 4 + r;
      int li2 = mr / 49, pos2 = mr - li2 * 49;
      int col = t * 16 + lc;
      out[(size_t)li2 * 3136 + col * 49 + pos2] =
          (half_t)fmaxf(acc[t][r] + b3[col], 0.f);
    }
  }
}

// ---------------- FC via MFMA: h = relu(A[2048,3136] @ wfc + bfc) -----------
// Unchanged (K=3136: panels too big for cache-direct; LDS tiling stays).
__global__ __launch_bounds__(256) void fc_mfma(
    const half_t* __restrict__ A, const half_t* __restrict__ Bt,
    const float* __restrict__ bias, float* __restrict__ C) {
  __shared__ __align__(16) half_t As[64 * 40];
  __shared__ __align__(16) half_t Bs[64 * 40];
  int tid = threadIdx.x;
  int m0 = blockIdx.y * 64, n0 = blockIdx.x * 64;
  int w = tid >> 6;
  int l = tid & 63;
  int lc = l & 15, q = l >> 4;
  int srow = tid >> 2, sseg = tid & 3;

  const half_t* aPtr = A + (size_t)(m0 + srow) * 3136 + sseg * 8;
  const half_t* bPtr = Bt + (size_t)(n0 + srow) * 3136 + sseg * 8;
  uint4 aReg = *(const uint4*)aPtr;
  uint4 bReg = *(const uint4*)bPtr;

  f32x4 acc[4];
#pragma unroll
  for (int t = 0; t < 4; ++t) acc[t] = (f32x4){0.f, 0.f, 0.f, 0.f};

  for (int k0 = 0; k0 < 3136; k0 += 32) {
    __syncthreads();
    *(uint4*)&As[srow * 40 + sseg * 8] = aReg;
    *(uint4*)&Bs[srow * 40 + sseg * 8] = bReg;
    __syncthreads();
    if (k0 + 32 < 3136) {                    // prefetch overlaps MFMA below
      aReg = *(const uint4*)(aPtr + k0 + 32);
      bReg = *(const uint4*)(bPtr + k0 + 32);
    }
    half8 af = *(const half8*)&As[(w * 16 + lc) * 40 + q * 8];
#pragma unroll
    for (int t = 0; t < 4; ++t) {
      half8 bf = *(const half8*)&Bs[(t * 16 + lc) * 40 + q * 8];
      acc[t] = __builtin_amdgcn_mfma_f32_16x16x32_f16(af, bf, acc[t], 0, 0, 0);
    }
  }
#pragma unroll
  for (int t = 0; t < 4; ++t) {
#pragma unroll
    for (int r = 0; r < 4; ++r) {
      int row = m0 + w * 16 + q * 4 + r;
      int col = n0 + t * 16 + lc;
      C[(size_t)row * 512 + col] = fmaxf(acc[t][r] + bias[col], 0.f);
    }
  }
}

// ---------------- wfeat = h @ Ww + bw : [2048,512]@[512,32] ----------------
__global__ __launch_bounds__(256) void wfeat_kernel(
    const float* __restrict__ h, const float* __restrict__ Ww,
    const float* __restrict__ bw, float* __restrict__ wf) {
  int g = blockIdx.x * 256 + threadIdx.x;   // 65536
  int row = g >> 5, oc = g & 31;
  float acc = bw[oc];
  const float* hr = h + (size_t)row * 512;
#pragma unroll 8
  for (int k = 0; k < 512; ++k) acc += hr[k] * Ww[k * 32 + oc];
  wf[g] = acc;
}

// ---------------- posfeat: one-hot MLP, one wave per row ----------------
__global__ __launch_bounds__(256) void posfeat_kernel(
    const int* __restrict__ pos, const float* __restrict__ wp1,
    const float* __restrict__ bp1, const float* __restrict__ wp2,
    const float* __restrict__ bp2, float* __restrict__ pf) {
  int row = (blockIdx.x * 256 + threadIdx.x) >> 6;  // 2048
  int l = threadIdx.x & 63;
  int p0 = pos[row * 2], p1 = pos[row * 2 + 1];
  float t1 = fmaxf(wp1[p0 * 64 + l] + wp1[(16 + p1) * 64 + l] + bp1[l], 0.f);
  float acc = bp2[l];
#pragma unroll
  for (int k = 0; k < 64; ++k) acc += __shfl(t1, k) * wp2[k * 64 + l];
  pf[row * 64 + l] = acc;
}

// ---------------- y0 = state0 @ [wpo1|wv1] : [64,8192]@[8192,128] ----------------
__global__ __launch_bounds__(256) void y0_kernel(
    const float* __restrict__ s0, const float* __restrict__ wpo1,
    const float* __restrict__ wv1, float* __restrict__ y0) {
  int g = blockIdx.x * 256 + threadIdx.x;   // 65536: (b, ks, n)
  int n = g & 127, ks = (g >> 7) & 7, b = g >> 10;
  const float* W = (n < 64) ? (wpo1 + n) : (wv1 + (n - 64));
  const float* s = s0 + (size_t)b * 8192 + ks * 1024;
  float acc = 0.f;
#pragma unroll 4
  for (int j = 0; j < 1024; ++j) acc += s[j] * W[(size_t)(ks * 1024 + j) * 64];
  atomicAdd(y0 + b * 128 + n, acc);
}

// ---------------- ystate: recurrence for hidden@W1 (cols 0..8191) ----------------
__global__ __launch_bounds__(128) void ystate_kernel(
    const float* __restrict__ y0, const float* __restrict__ done,
    const int* __restrict__ pos, const float* __restrict__ wf,
    const float* __restrict__ wpo1, const float* __restrict__ wv1,
    float* __restrict__ ys) {
  int b = blockIdx.x;
  int n = threadIdx.x;                      // 0..127
  const float* W = (n < 64) ? (wpo1 + n) : (wv1 + (n - 64));
  float y = y0[b * 128 + n];
  for (int t = 0; t < TT; ++t) {
    int row = t * BB + b;
    float mask = 1.f - done[row];
    int off = pos[row * 2] * 16 + pos[row * 2 + 1];
    y *= mask;
    const float* wfr = wf + row * 32;
#pragma unroll
    for (int c = 0; c < 32; ++c) y += wfr[c] * W[(size_t)(c * 256 + off) * 64];
    ys[(size_t)row * 128 + n] = y;
  }
}

// ---------------- final map state (output 2) ----------------
__global__ __launch_bounds__(256) void state_kernel(
    const float* __restrict__ s0, const float* __restrict__ done,
    const int* __restrict__ pos, const float* __restrict__ wf,
    float* __restrict__ out_state) {
  int b = blockIdx.x, tid = threadIdx.x;    // tid = spatial offset 0..255
  float s[32];
#pragma unroll
  for (int c = 0; c < 32; ++c) s[c] = s0[(size_t)b * 8192 + c * 256 + tid];
  for (int t = 0; t < TT; ++t) {
    int row = t * BB + b;
    float mask = 1.f - done[row];
    int off = pos[row * 2] * 16 + pos[row * 2 + 1];
#pragma unroll
    for (int c = 0; c < 32; ++c) s[c] *= mask;
    if (tid == off) {
#pragma unroll
      for (int c = 0; c < 32; ++c) s[c] += wf[row * 32 + c];
    }
  }
#pragma unroll
  for (int c = 0; c < 32; ++c) out_state[(size_t)b * 8192 + c * 256 + tid] = s[c];
}

// ---------------- heads: + pos-part of W1, ReLU, second layers ----------------
__global__ __launch_bounds__(256) void head_kernel(
    const float* __restrict__ ys, const float* __restrict__ pf,
    const float* __restrict__ wpo1, const float* __restrict__ wv1,
    const float* __restrict__ bpo1, const float* __restrict__ bv1,
    const float* __restrict__ wpo2, const float* __restrict__ bpo2,
    const float* __restrict__ wv2, const float* __restrict__ bv2,
    float* __restrict__ logits, float* __restrict__ vout) {
  int row = (blockIdx.x * 256 + threadIdx.x) >> 6;  // one wave per row
  int l = threadIdx.x & 63;
  float pfv = pf[row * 64 + l];
  float accp = bpo1[l] + ys[(size_t)row * 128 + l];
  float accv = bv1[l] + ys[(size_t)row * 128 + 64 + l];
#pragma unroll
  for (int k = 0; k < 64; ++k) {
    float pk = __shfl(pfv, k);
    accp += pk * wpo1[(size_t)(8192 + k) * 64 + l];
    accv += pk * wv1[(size_t)(8192 + k) * 64 + l];
  }
  float rp = fmaxf(accp, 0.f), rv = fmaxf(accv, 0.f);
#pragma unroll
  for (int a = 0; a < 5; ++a) {
    float pa = rp * wpo2[l * 5 + a];
#pragma unroll
    for (int m = 32; m >= 1; m >>= 1) pa += __shfl_xor(pa, m);
    if (l == 0) logits[row * 5 + a] = pa + bpo2[a];
  }
  float pv = rv * wv2[l];
#pragma unroll
  for (int m = 32; m >= 1; m >>= 1) pv += __shfl_xor(pv, m);
  if (l == 0) vout[row] = pv + bv2[0];
}

extern "C" void kernel_launch(void* const* d_in, const int* in_sizes, int n_in,
                              void* d_out, int out_size, void* d_ws, size_t ws_size,
                              hipStream_t stream) {
  const float* image = (const float*)d_in[0];
  const float* done = (const float*)d_in[1];
  const float* state0 = (const float*)d_in[2];
  const int* position = (const int*)d_in[3];
  const float* w1 = (const float*)d_in[4];
  const float* b1 = (const float*)d_in[5];
  const float* w2 = (const float*)d_in[6];
  const float* b2 = (const float*)d_in[7];
  const float* w3 = (const float*)d_in[8];
  const float* b3 = (const float*)d_in[9];
  const float* wfc = (const float*)d_in[10];
  const float* bfc = (const float*)d_in[11];
  const float* Ww = (const float*)d_in[12];
  const float* bw = (const float*)d_in[13];
  const float* wp1 = (const float*)d_in[14];
  const float* bp1 = (const float*)d_in[15];
  const float* wp2 = (const float*)d_in[16];
  const float* bp2 = (const float*)d_in[17];
  const float* wpo1 = (const float*)d_in[18];
  const float* bpo1 = (const float*)d_in[19];
  const float* wpo2 = (const float*)d_in[20];
  const float* bpo2 = (const float*)d_in[21];
  const float* wv1 = (const float*)d_in[22];
  const float* bv1 = (const float*)d_in[23];
  const float* wv2 = (const float*)d_in[24];
  const float* bv2 = (const float*)d_in[25];

  float* ws = (float*)d_ws;
  half_t* w1p = (half_t*)(ws + OFF_W1T);
  half_t* w2T = (half_t*)(ws + OFF_W2T);
  half_t* w3T = (half_t*)(ws + OFF_W3T);
  float* wf = ws + OFF_WF;
  float* pfb = ws + OFF_PF;
  float* y0 = ws + OFF_Y0;
  float* ysb = ws + OFF_YS;
  float* h = ws + OFF_H;
  half_t* wfcT = (half_t*)(ws + OFF_WFCT);
  half_t* c3b = (half_t*)(ws + OFF_C3);
  half_t* c2b = (half_t*)(ws + OFF_C2);
  half_t* c1b = (half_t*)(ws + OFF_C1);

  float* out = (float*)d_out;
  float* out_logits = out;            // [2048,5]
  float* out_v = out + 10240;         // [2048,1]
  float* out_state = out + 12288;     // [64,32,16,16]

  // Tier by ws_size (floats): A: CS=2048 no chunk, 95.9 MB;
  //                           B: CS=1024, 69.7 MB; C: CS=512, 56.6 MB.
  int CS;
  if (ws_size >= (size_t)23986176 * 4) CS = 2048;
  else if (ws_size >= (size_t)17432576 * 4) CS = 1024;
  else CS = 512;
  int nc = TBR / CS;

  hipMemsetAsync(y0, 0, 8192 * sizeof(float), stream);
  prep_kernel<<<304, 256, 0, stream>>>(w1, w2, w3, w1p, w2T, w3T);
  prep_wfct<<<dim3(98, 16), 256, 0, stream>>>(wfc, wfcT);

  for (int c = 0; c < nc; ++c) {
    int n0 = c * CS;
    conv1_mfma<<<CS * 400 / 64, 256, 0, stream>>>(image, w1p, b1, c1b, n0);
    conv2_mfma<<<CS * 81 / 64, 256, 0, stream>>>(
        c1b, w2T, b2, c2b + (size_t)n0 * 5184);
  }
  conv3_mfma<<<TBR * 49 / 64, 256, 0, stream>>>(c2b, w3T, b3, c3b);
  fc_mfma<<<dim3(8, 32), 256, 0, stream>>>(c3b, wfcT, bfc, h);
  wfeat_kernel<<<256, 256, 0, stream>>>(h, Ww, bw, wf);
  posfeat_kernel<<<512, 256, 0, stream>>>(position, wp1, bp1, wp2, bp2, pfb);
  y0_kernel<<<256, 256, 0, stream>>>(state0, wpo1, wv1, y0);
  ystate_kernel<<<64, 128, 0, stream>>>(y0, done, position, wf, wpo1, wv1, ysb);
  state_kernel<<<64, 256, 0, stream>>>(state0, done, position, wf, out_state);
  head_kernel<<<512, 256, 0, stream>>>(ysb, pfb, wpo1, wv1, bpo1, bv1,
                                       wpo2, bpo2, wv2, bv2, out_logits, out_v);
}

// Round 4
// 596.099 us; speedup vs baseline: 1.1701x; 1.1701x over previous
//
#include <hip/hip_runtime.h>
#include <hip/hip_bf16.h>

// MapAgent: NatureCNN (3 convs + FC) -> map-write scan -> policy/value heads.
// T=32, B=64, TB=2048.
//
// R11 changes:
//  * REVERT conv2/conv3 to R9 LDS-staged forms (R10's LDS-less versions cost
//    ~75us: B is shared data; per-wave L1 re-reads saturate VMEM. Lesson.)
//  * conv1: three schedules all ~110us with identical FETCH=114MB @1.55TB/s
//    -> bottleneck is the ACCESS PATTERN's achievable HBM BW (816B scattered
//    runs, 2x refetch), not scheduling. New structure: one block per image,
//    stream 5 vertical bands (20 rows = 5040 floats) through double-buffered
//    LDS (2x10KB) as contiguous 4KB sweeps; compute all 400 outputs from LDS
//    (5 M-tiles/band x 8 taps x 2 MFMA; B in 64 VGPRs reused for 25 tiles).
//    Each block owns its rows exclusively -> FETCH ~114->~60MB, streaming.

#define TT 32
#define BB 64
#define TBR 2048

typedef _Float16 half_t;
typedef __attribute__((ext_vector_type(4))) _Float16 half4;
typedef __attribute__((ext_vector_type(8))) _Float16 half8;
typedef __attribute__((ext_vector_type(4))) float f32x4;

// ---- workspace offsets (floats) ----
#define OFF_W1T   0u          // 4096    : w1p fp16 [tap8][oc32][k32] zero-pad
#define OFF_W2T   6144u       // 16384   : w2T fp16 [tap16][oc64][c32]
#define OFF_W3T   22528u      // 18432   : w3T fp16 [tap9][oc64][c64]
#define OFF_WF    40960u      // 65536   : wfeat [2048][32]
#define OFF_PF    106496u     // 131072  : posfeat [2048][64]
#define OFF_Y0    237568u     // 8192    : y0 [64][128]
#define OFF_YS    245760u     // 262144  : ystate [2048][128]
#define OFF_H     507904u     // 1048576 : h [2048][512]
#define OFF_WFCT  1556480u    // 802816  : wfcT fp16 [512][3136] (k=c*49+pos)
#define OFF_C3    2359296u    // 3211264 : c3b fp16 [2048][3136]
#define OFF_C2    5570560u    // 5308416 : c2b fp16 [2048][9][9][64]
#define OFF_C1    10878976u   // c1b fp16 [CS][20][20][32]

// ---------------- weight prep ----------------
__global__ __launch_bounds__(256) void prep_kernel(
    const float* __restrict__ w1, const float* __restrict__ w2,
    const float* __restrict__ w3, half_t* __restrict__ w1p,
    half_t* __restrict__ w2T, half_t* __restrict__ w3T) {
  int g = blockIdx.x * 256 + threadIdx.x;   // 77824 total
  if (g < 8192) {
    // w1p[(tap*32+oc)*32+kk], kk = kx*3+c (<24) else 0 ; w1 is [oc][c][ky*8+kx]
    int kk = g & 31, oc = (g >> 5) & 31, tap = g >> 10;
    half_t v = (half_t)0.f;
    if (kk < 24) {
      int kx = kk / 3, c = kk - 3 * kx;
      v = (half_t)(w1[oc * 192 + c * 64 + tap * 8 + kx] * (1.0f / 255.0f));
    }
    w1p[g] = v;
    return;
  }
  int g2 = g - 8192;
  if (g2 < 32768) {                          // w2T[(tap*64+oc)*32+c]
    int c = g2 & 31, oc = (g2 >> 5) & 63, tap = g2 >> 11;
    w2T[g2] = (half_t)w2[oc * 512 + c * 16 + tap];
    return;
  }
  int g3 = g2 - 32768;
  if (g3 < 36864) {                          // w3T[(tap*64+oc)*64+c]
    int c = g3 & 63, oc = (g3 >> 6) & 63, tap = g3 >> 12;
    w3T[g3] = (half_t)w3[oc * 576 + c * 9 + tap];
  }
}

// ---- wfcT[n][k] = (half)wfc[k][n], k = c*49+pos : LDS-tiled transpose ----
__global__ __launch_bounds__(256) void prep_wfct(
    const float* __restrict__ wfc, half_t* __restrict__ wfcT) {
  __shared__ float t[32][33];
  int k0 = blockIdx.x * 32, n0 = blockIdx.y * 32;
  int tx = threadIdx.x & 31, ty = threadIdx.x >> 5;  // ty 0..7
#pragma unroll
  for (int i = 0; i < 4; ++i)
    t[ty + 8 * i][tx] = wfc[(size_t)(k0 + ty + 8 * i) * 512 + n0 + tx];
  __syncthreads();
#pragma unroll
  for (int i = 0; i < 4; ++i)
    wfcT[(size_t)(n0 + ty + 8 * i) * 3136 + k0 + tx] =
        (half_t)t[tx][ty + 8 * i];
}

// ---------------- conv1: one block per image, banded streaming ----------
// Input rows of band b: 16b..16b+19 (floats ib+4032b .. +5040). Outputs of
// band b: oy 4b..4b+3 = 80 rows = 5 M-tiles of 16. Lane (lc,q) of a tile:
// A row lp=tile*16+lc -> (oyl,ox); taps ky: 8 halfs at
// lds[(4*oyl+ky)*252 + 12*ox + q*8] (q==3 = K-pad zeros, weights also 0).
#define C1_BANDF 5040
#define C1_BANDV 1260
__global__ __launch_bounds__(256) void conv1_mfma(
    const float* __restrict__ img, const half_t* __restrict__ w1p,
    const float* __restrict__ b1, half_t* __restrict__ out, int n0) {
  __shared__ __align__(16) half_t As[2][C1_BANDF];
  int tid = threadIdx.x;
  int li = blockIdx.x;
  int w = tid >> 6, l = tid & 63, lc = l & 15, q = l >> 4;
  const float* ib = img + (size_t)(n0 + li) * 21168;
  half_t* ob = out + (size_t)li * 400 * 32;

  // B fragments in registers, once per block, reused for all 25 tiles
  half8 bfrag[8][2];
#pragma unroll
  for (int tap = 0; tap < 8; ++tap)
#pragma unroll
    for (int t = 0; t < 2; ++t)
      bfrag[tap][t] =
          *(const half8*)(w1p + (size_t)(tap * 32 + t * 16 + lc) * 32 + q * 8);
  float b1v[2] = {b1[lc], b1[16 + lc]};

  f32x4 fr[5];                                // staging registers
#define C1_LOADB(b)                                                   \
  {                                                                   \
    const float* src = ib + 4032 * (b);                               \
    _Pragma("unroll") for (int i = 0; i < 5; ++i) {                   \
      int g = tid + 256 * i;                                          \
      if (g < C1_BANDV) fr[i] = *(const f32x4*)(src + 4 * g);         \
    }                                                                 \
  }
#define C1_WRITEB(buf)                                                \
  {                                                                   \
    _Pragma("unroll") for (int i = 0; i < 5; ++i) {                   \
      int g = tid + 256 * i;                                          \
      if (g < C1_BANDV) {                                             \
        half4 o;                                                      \
        _Pragma("unroll") for (int j = 0; j < 4; ++j)                 \
            o[j] = (half_t)fr[i][j];                                  \
        *(half4*)&As[buf][4 * g] = o;                                 \
      }                                                               \
    }                                                                 \
  }

  C1_LOADB(0);
  C1_WRITEB(0);
  for (int b = 0; b < 5; ++b) {
    if (b < 4) C1_LOADB(b + 1);               // global loads span barrier+MFMA
    __syncthreads();                          // band b staged & visible
    int buf = b & 1;
    for (int tile = w; tile < 5; tile += 4) { // 5 tiles over 4 waves
      int lp = tile * 16 + lc;
      int oyl = lp / 20, ox = lp - oyl * 20;
      f32x4 acc[2];
      acc[0] = (f32x4){0.f, 0.f, 0.f, 0.f};
      acc[1] = (f32x4){0.f, 0.f, 0.f, 0.f};
#pragma unroll
      for (int ky = 0; ky < 8; ++ky) {
        half8 af;
        if (q < 3) {
          const half_t* p = &As[buf][(4 * oyl + ky) * 252 + 12 * ox + q * 8];
          *(half4*)&af = *(const half4*)p;          // 8B-aligned b64 reads
          *((half4*)&af + 1) = *((const half4*)(p + 4));
        } else {
#pragma unroll
          for (int j = 0; j < 8; ++j) af[j] = (half_t)0.f;
        }
        acc[0] = __builtin_amdgcn_mfma_f32_16x16x32_f16(af, bfrag[ky][0],
                                                        acc[0], 0, 0, 0);
        acc[1] = __builtin_amdgcn_mfma_f32_16x16x32_f16(af, bfrag[ky][1],
                                                        acc[1], 0, 0, 0);
      }
      // C: row=q*4+r (within tile), col=t*16+lc [m89]; out [m][32]
#pragma unroll
      for (int t = 0; t < 2; ++t) {
#pragma unroll
        for (int r = 0; r < 4; ++r) {
          int mr = b * 80 + tile * 16 + q * 4 + r;
          ob[(size_t)mr * 32 + t * 16 + lc] =
              (half_t)fmaxf(acc[t][r] + b1v[t], 0.f);
        }
      }
    }
    if (b < 4) C1_WRITEB((b + 1) & 1);        // other buffer; safe post-barrier
  }
}

// ---------------- conv2 implicit-GEMM MFMA: -> fp16 [li][9][9][64] ----------
// M-tile 64 x N=64, 4 waves, 16 taps x K=32. A row = in[li][2oy+ky][2ox+kx][:].
__global__ __launch_bounds__(256) void conv2_mfma(
    const half_t* __restrict__ in, const half_t* __restrict__ w2T,
    const float* __restrict__ b2, half_t* __restrict__ out) {
  __shared__ __align__(16) half_t As[64 * 40];
  __shared__ __align__(16) half_t Bs[64 * 40];
  int tid = threadIdx.x;
  int m0 = blockIdx.x * 64;
  int w = tid >> 6, l = tid & 63, lc = l & 15, q = l >> 4;
  int srow = tid >> 2, sseg = tid & 3;
  int m = m0 + srow;
  int li = m / 81, pos = m - li * 81;
  int oy = pos / 9, ox = pos - (pos / 9) * 9;
  const half_t* aBase = in + (size_t)((li * 20 + 2 * oy) * 20 + 2 * ox) * 32 + sseg * 8;
  const half_t* bBase = w2T + srow * 32 + sseg * 8;
  uint4 aReg = *(const uint4*)aBase;          // tap 0
  uint4 bReg = *(const uint4*)bBase;
  f32x4 acc[4];
#pragma unroll
  for (int t = 0; t < 4; ++t) acc[t] = (f32x4){0.f, 0.f, 0.f, 0.f};
#pragma unroll
  for (int tap = 0; tap < 16; ++tap) {
    __syncthreads();
    *(uint4*)&As[srow * 40 + sseg * 8] = aReg;
    *(uint4*)&Bs[srow * 40 + sseg * 8] = bReg;
    __syncthreads();
    if (tap < 15) {                           // prefetch next tap
      int nt = tap + 1, ky = nt >> 2, kx = nt & 3;
      aReg = *(const uint4*)(aBase + (ky * 20 + kx) * 32);
      bReg = *(const uint4*)(bBase + nt * 2048);
    }
    half8 af = *(const half8*)&As[(w * 16 + lc) * 40 + q * 8];
#pragma unroll
    for (int t = 0; t < 4; ++t) {
      half8 bf = *(const half8*)&Bs[(t * 16 + lc) * 40 + q * 8];
      acc[t] = __builtin_amdgcn_mfma_f32_16x16x32_f16(af, bf, acc[t], 0, 0, 0);
    }
  }
  // C: row=w*16+q*4+r, col=t*16+lc [m89]; out offset = m*64+col (layout [m][c])
#pragma unroll
  for (int t = 0; t < 4; ++t) {
#pragma unroll
    for (int r = 0; r < 4; ++r) {
      int mr = m0 + w * 16 + q * 4 + r;
      int col = t * 16 + lc;
      out[(size_t)mr * 64 + col] = (half_t)fmaxf(acc[t][r] + b2[col], 0.f);
    }
  }
}

// ---------------- conv3 implicit-GEMM MFMA: -> fp16 [li][c*49+pos] ----------
// M-tile 64 x N=64, 9 taps x 2 chunks x K=32. A row = in[li][oy+ky][ox+kx][:].
__global__ __launch_bounds__(256) void conv3_mfma(
    const half_t* __restrict__ in, const half_t* __restrict__ w3T,
    const float* __restrict__ b3, half_t* __restrict__ out) {
  __shared__ __align__(16) half_t As[64 * 40];
  __shared__ __align__(16) half_t Bs[64 * 40];
  int tid = threadIdx.x;
  int m0 = blockIdx.x * 64;
  int w = tid >> 6, l = tid & 63, lc = l & 15, q = l >> 4;
  int srow = tid >> 2, sseg = tid & 3;
  int m = m0 + srow;
  int li = m / 49, pos = m - li * 49;
  int oy = pos / 7, ox = pos - (pos / 7) * 7;
  const half_t* aBase = in + (size_t)((li * 9 + oy) * 9 + ox) * 64 + sseg * 8;
  const half_t* bBase = w3T + srow * 64 + sseg * 8;
  uint4 aReg = *(const uint4*)aBase;          // s=0: tap0 chunk0
  uint4 bReg = *(const uint4*)bBase;
  f32x4 acc[4];
#pragma unroll
  for (int t = 0; t < 4; ++t) acc[t] = (f32x4){0.f, 0.f, 0.f, 0.f};
#pragma unroll
  for (int s = 0; s < 18; ++s) {
    __syncthreads();
    *(uint4*)&As[srow * 40 + sseg * 8] = aReg;
    *(uint4*)&Bs[srow * 40 + sseg * 8] = bReg;
    __syncthreads();
    if (s < 17) {                             // prefetch next (tap,chunk)
      int ns = s + 1, tap = ns >> 1, ch = ns & 1;
      int ky = tap / 3, kx = tap - ky * 3;
      aReg = *(const uint4*)(aBase + ((ky * 9 + kx) * 64 + ch * 32));
      bReg = *(const uint4*)(bBase + (tap * 4096 + ch * 32));
    }
    half8 af = *(const half8*)&As[(w * 16 + lc) * 40 + q * 8];
#pragma unroll
    for (int t = 0; t < 4; ++t) {
      half8 bf = *(const half8*)&Bs[(t * 16 + lc) * 40 + q * 8];
      acc[t] = __builtin_amdgcn_mfma_f32_16x16x32_f16(af, bf, acc[t], 0, 0, 0);
    }
  }
  // write k-order c*49+pos (fc_mfma consumes this order; wfcT unchanged)
#pragma unroll
  for (int t = 0; t < 4; ++t) {
#pragma unroll
    for (int r = 0; r < 4; ++r) {
      int mr = m0 + w * 16 + q * 4 + r;
      int li2 = mr / 49, pos2 = mr - li2 * 49;
      int col = t * 16 + lc;
      out[(size_t)li2 * 3136 + col * 49 + pos2] =
          (half_t)fmaxf(acc[t][r] + b3[col], 0.f);
    }
  }
}

// ---------------- FC via MFMA: h = relu(A[2048,3136] @ wfc + bfc) -----------
// Unchanged from R6 (proven). A fp16 rows k=c*49+pos, Bt=wfcT fp16 [512][3136].
__global__ __launch_bounds__(256) void fc_mfma(
    const half_t* __restrict__ A, const half_t* __restrict__ Bt,
    const float* __restrict__ bias, float* __restrict__ C) {
  __shared__ __align__(16) half_t As[64 * 40];
  __shared__ __align__(16) half_t Bs[64 * 40];
  int tid = threadIdx.x;
  int m0 = blockIdx.y * 64, n0 = blockIdx.x * 64;
  int w = tid >> 6;
  int l = tid & 63;
  int lc = l & 15, q = l >> 4;
  int srow = tid >> 2, sseg = tid & 3;

  const half_t* aPtr = A + (size_t)(m0 + srow) * 3136 + sseg * 8;
  const half_t* bPtr = Bt + (size_t)(n0 + srow) * 3136 + sseg * 8;
  uint4 aReg = *(const uint4*)aPtr;
  uint4 bReg = *(const uint4*)bPtr;

  f32x4 acc[4];
#pragma unroll
  for (int t = 0; t < 4; ++t) acc[t] = (f32x4){0.f, 0.f, 0.f, 0.f};

  for (int k0 = 0; k0 < 3136; k0 += 32) {
    __syncthreads();
    *(uint4*)&As[srow * 40 + sseg * 8] = aReg;
    *(uint4*)&Bs[srow * 40 + sseg * 8] = bReg;
    __syncthreads();
    if (k0 + 32 < 3136) {                    // prefetch overlaps MFMA below
      aReg = *(const uint4*)(aPtr + k0 + 32);
      bReg = *(const uint4*)(bPtr + k0 + 32);
    }
    half8 af = *(const half8*)&As[(w * 16 + lc) * 40 + q * 8];
#pragma unroll
    for (int t = 0; t < 4; ++t) {
      half8 bf = *(const half8*)&Bs[(t * 16 + lc) * 40 + q * 8];
      acc[t] = __builtin_amdgcn_mfma_f32_16x16x32_f16(af, bf, acc[t], 0, 0, 0);
    }
  }
#pragma unroll
  for (int t = 0; t < 4; ++t) {
#pragma unroll
    for (int r = 0; r < 4; ++r) {
      int row = m0 + w * 16 + q * 4 + r;
      int col = n0 + t * 16 + lc;
      C[(size_t)row * 512 + col] = fmaxf(acc[t][r] + bias[col], 0.f);
    }
  }
}

// ---------------- wfeat = h @ Ww + bw : [2048,512]@[512,32] ----------------
__global__ __launch_bounds__(256) void wfeat_kernel(
    const float* __restrict__ h, const float* __restrict__ Ww,
    const float* __restrict__ bw, float* __restrict__ wf) {
  int g = blockIdx.x * 256 + threadIdx.x;   // 65536
  int row = g >> 5, oc = g & 31;
  float acc = bw[oc];
  const float* hr = h + (size_t)row * 512;
#pragma unroll 8
  for (int k = 0; k < 512; ++k) acc += hr[k] * Ww[k * 32 + oc];
  wf[g] = acc;
}

// ---------------- posfeat: one-hot MLP, one wave per row ----------------
__global__ __launch_bounds__(256) void posfeat_kernel(
    const int* __restrict__ pos, const float* __restrict__ wp1,
    const float* __restrict__ bp1, const float* __restrict__ wp2,
    const float* __restrict__ bp2, float* __restrict__ pf) {
  int row = (blockIdx.x * 256 + threadIdx.x) >> 6;  // 2048
  int l = threadIdx.x & 63;
  int p0 = pos[row * 2], p1 = pos[row * 2 + 1];
  float t1 = fmaxf(wp1[p0 * 64 + l] + wp1[(16 + p1) * 64 + l] + bp1[l], 0.f);
  float acc = bp2[l];
#pragma unroll
  for (int k = 0; k < 64; ++k) acc += __shfl(t1, k) * wp2[k * 64 + l];
  pf[row * 64 + l] = acc;
}

// ---------------- y0 = state0 @ [wpo1|wv1] : [64,8192]@[8192,128] ----------------
__global__ __launch_bounds__(256) void y0_kernel(
    const float* __restrict__ s0, const float* __restrict__ wpo1,
    const float* __restrict__ wv1, float* __restrict__ y0) {
  int g = blockIdx.x * 256 + threadIdx.x;   // 65536: (b, ks, n)
  int n = g & 127, ks = (g >> 7) & 7, b = g >> 10;
  const float* W = (n < 64) ? (wpo1 + n) : (wv1 + (n - 64));
  const float* s = s0 + (size_t)b * 8192 + ks * 1024;
  float acc = 0.f;
#pragma unroll 4
  for (int j = 0; j < 1024; ++j) acc += s[j] * W[(size_t)(ks * 1024 + j) * 64];
  atomicAdd(y0 + b * 128 + n, acc);
}

// ---------------- ystate: recurrence for hidden@W1 (cols 0..8191) ----------------
__global__ __launch_bounds__(128) void ystate_kernel(
    const float* __restrict__ y0, const float* __restrict__ done,
    const int* __restrict__ pos, const float* __restrict__ wf,
    const float* __restrict__ wpo1, const float* __restrict__ wv1,
    float* __restrict__ ys) {
  int b = blockIdx.x;
  int n = threadIdx.x;                      // 0..127
  const float* W = (n < 64) ? (wpo1 + n) : (wv1 + (n - 64));
  float y = y0[b * 128 + n];
  for (int t = 0; t < TT; ++t) {
    int row = t * BB + b;
    float mask = 1.f - done[row];
    int off = pos[row * 2] * 16 + pos[row * 2 + 1];
    y *= mask;
    const float* wfr = wf + row * 32;
#pragma unroll
    for (int c = 0; c < 32; ++c) y += wfr[c] * W[(size_t)(c * 256 + off) * 64];
    ys[(size_t)row * 128 + n] = y;
  }
}

// ---------------- final map state (output 2) ----------------
__global__ __launch_bounds__(256) void state_kernel(
    const float* __restrict__ s0, const float* __restrict__ done,
    const int* __restrict__ pos, const float* __restrict__ wf,
    float* __restrict__ out_state) {
  int b = blockIdx.x, tid = threadIdx.x;    // tid = spatial offset 0..255
  float s[32];
#pragma unroll
  for (int c = 0; c < 32; ++c) s[c] = s0[(size_t)b * 8192 + c * 256 + tid];
  for (int t = 0; t < TT; ++t) {
    int row = t * BB + b;
    float mask = 1.f - done[row];
    int off = pos[row * 2] * 16 + pos[row * 2 + 1];
#pragma unroll
    for (int c = 0; c < 32; ++c) s[c] *= mask;
    if (tid == off) {
#pragma unroll
      for (int c = 0; c < 32; ++c) s[c] += wf[row * 32 + c];
    }
  }
#pragma unroll
  for (int c = 0; c < 32; ++c) out_state[(size_t)b * 8192 + c * 256 + tid] = s[c];
}

// ---------------- heads: + pos-part of W1, ReLU, second layers ----------------
__global__ __launch_bounds__(256) void head_kernel(
    const float* __restrict__ ys, const float* __restrict__ pf,
    const float* __restrict__ wpo1, const float* __restrict__ wv1,
    const float* __restrict__ bpo1, const float* __restrict__ bv1,
    const float* __restrict__ wpo2, const float* __restrict__ bpo2,
    const float* __restrict__ wv2, const float* __restrict__ bv2,
    float* __restrict__ logits, float* __restrict__ vout) {
  int row = (blockIdx.x * 256 + threadIdx.x) >> 6;  // one wave per row
  int l = threadIdx.x & 63;
  float pfv = pf[row * 64 + l];
  float accp = bpo1[l] + ys[(size_t)row * 128 + l];
  float accv = bv1[l] + ys[(size_t)row * 128 + 64 + l];
#pragma unroll
  for (int k = 0; k < 64; ++k) {
    float pk = __shfl(pfv, k);
    accp += pk * wpo1[(size_t)(8192 + k) * 64 + l];
    accv += pk * wv1[(size_t)(8192 + k) * 64 + l];
  }
  float rp = fmaxf(accp, 0.f), rv = fmaxf(accv, 0.f);
#pragma unroll
  for (int a = 0; a < 5; ++a) {
    float pa = rp * wpo2[l * 5 + a];
#pragma unroll
    for (int m = 32; m >= 1; m >>= 1) pa += __shfl_xor(pa, m);
    if (l == 0) logits[row * 5 + a] = pa + bpo2[a];
  }
  float pv = rv * wv2[l];
#pragma unroll
  for (int m = 32; m >= 1; m >>= 1) pv += __shfl_xor(pv, m);
  if (l == 0) vout[row] = pv + bv2[0];
}

extern "C" void kernel_launch(void* const* d_in, const int* in_sizes, int n_in,
                              void* d_out, int out_size, void* d_ws, size_t ws_size,
                              hipStream_t stream) {
  const float* image = (const float*)d_in[0];
  const float* done = (const float*)d_in[1];
  const float* state0 = (const float*)d_in[2];
  const int* position = (const int*)d_in[3];
  const float* w1 = (const float*)d_in[4];
  const float* b1 = (const float*)d_in[5];
  const float* w2 = (const float*)d_in[6];
  const float* b2 = (const float*)d_in[7];
  const float* w3 = (const float*)d_in[8];
  const float* b3 = (const float*)d_in[9];
  const float* wfc = (const float*)d_in[10];
  const float* bfc = (const float*)d_in[11];
  const float* Ww = (const float*)d_in[12];
  const float* bw = (const float*)d_in[13];
  const float* wp1 = (const float*)d_in[14];
  const float* bp1 = (const float*)d_in[15];
  const float* wp2 = (const float*)d_in[16];
  const float* bp2 = (const float*)d_in[17];
  const float* wpo1 = (const float*)d_in[18];
  const float* bpo1 = (const float*)d_in[19];
  const float* wpo2 = (const float*)d_in[20];
  const float* bpo2 = (const float*)d_in[21];
  const float* wv1 = (const float*)d_in[22];
  const float* bv1 = (const float*)d_in[23];
  const float* wv2 = (const float*)d_in[24];
  const float* bv2 = (const float*)d_in[25];

  float* ws = (float*)d_ws;
  half_t* w1p = (half_t*)(ws + OFF_W1T);
  half_t* w2T = (half_t*)(ws + OFF_W2T);
  half_t* w3T = (half_t*)(ws + OFF_W3T);
  float* wf = ws + OFF_WF;
  float* pfb = ws + OFF_PF;
  float* y0 = ws + OFF_Y0;
  float* ysb = ws + OFF_YS;
  float* h = ws + OFF_H;
  half_t* wfcT = (half_t*)(ws + OFF_WFCT);
  half_t* c3b = (half_t*)(ws + OFF_C3);
  half_t* c2b = (half_t*)(ws + OFF_C2);
  half_t* c1b = (half_t*)(ws + OFF_C1);

  float* out = (float*)d_out;
  float* out_logits = out;            // [2048,5]
  float* out_v = out + 10240;         // [2048,1]
  float* out_state = out + 12288;     // [64,32,16,16]

  // Tier by ws_size (floats): A: CS=2048 no chunk, 95.9 MB;
  //                           B: CS=1024, 69.7 MB; C: CS=512, 56.6 MB.
  int CS;
  if (ws_size >= (size_t)23986176 * 4) CS = 2048;
  else if (ws_size >= (size_t)17432576 * 4) CS = 1024;
  else CS = 512;
  int nc = TBR / CS;

  hipMemsetAsync(y0, 0, 8192 * sizeof(float), stream);
  prep_kernel<<<304, 256, 0, stream>>>(w1, w2, w3, w1p, w2T, w3T);
  prep_wfct<<<dim3(98, 16), 256, 0, stream>>>(wfc, wfcT);

  for (int c = 0; c < nc; ++c) {
    int n0 = c * CS;
    conv1_mfma<<<CS, 256, 0, stream>>>(image, w1p, b1, c1b, n0);
    conv2_mfma<<<CS * 81 / 64, 256, 0, stream>>>(
        c1b, w2T, b2, c2b + (size_t)n0 * 5184);
  }
  conv3_mfma<<<TBR * 49 / 64, 256, 0, stream>>>(c2b, w3T, b3, c3b);
  fc_mfma<<<dim3(8, 32), 256, 0, stream>>>(c3b, wfcT, bfc, h);
  wfeat_kernel<<<256, 256, 0, stream>>>(h, Ww, bw, wf);
  posfeat_kernel<<<512, 256, 0, stream>>>(position, wp1, bp1, wp2, bp2, pfb);
  y0_kernel<<<256, 256, 0, stream>>>(state0, wpo1, wv1, y0);
  ystate_kernel<<<64, 128, 0, stream>>>(y0, done, position, wf, wpo1, wv1, ysb);
  state_kernel<<<64, 256, 0, stream>>>(state0, done, position, wf, out_state);
  head_kernel<<<512, 256, 0, stream>>>(ysb, pfb, wpo1, wv1, bpo1, bv1,
                                       wpo2, bpo2, wv2, bv2, out_logits, out_v);
}

// Round 5
// 524.787 us; speedup vs baseline: 1.3291x; 1.1359x over previous
//
#include <hip/hip_runtime.h>
#include <hip/hip_bf16.h>

// MapAgent: NatureCNN (3 convs + FC) -> map-write scan -> policy/value heads.
// T=32, B=64, TB=2048.
//
// R12 change (theory: y0_kernel now the top dispatch at ~105us with Occ=11%,
// VALU 2.3%, HBM 0.7% -- 256 blocks = 1 block/CU, latency-bound on L2 W-reads
// with 1024-deep serial K loop. Floor is ~8us of L2 bandwidth):
//  * y0_kernel: K-split 8x deeper. Grid 64b x 32 K-chunks = 2048 blocks
//    (8/CU, full occupancy); 256 thr = 2 kh x 128 n; each thread K=128;
//    LDS pair-reduce kh; one atomicAdd per (block,n) -> 32 atomics/address.
//  * Everything else unchanged (conv1 banded streaming, conv2/3 R9 LDS forms).

#define TT 32
#define BB 64
#define TBR 2048

typedef _Float16 half_t;
typedef __attribute__((ext_vector_type(4))) _Float16 half4;
typedef __attribute__((ext_vector_type(8))) _Float16 half8;
typedef __attribute__((ext_vector_type(4))) float f32x4;

// ---- workspace offsets (floats) ----
#define OFF_W1T   0u          // 4096    : w1p fp16 [tap8][oc32][k32] zero-pad
#define OFF_W2T   6144u       // 16384   : w2T fp16 [tap16][oc64][c32]
#define OFF_W3T   22528u      // 18432   : w3T fp16 [tap9][oc64][c64]
#define OFF_WF    40960u      // 65536   : wfeat [2048][32]
#define OFF_PF    106496u     // 131072  : posfeat [2048][64]
#define OFF_Y0    237568u     // 8192    : y0 [64][128]
#define OFF_YS    245760u     // 262144  : ystate [2048][128]
#define OFF_H     507904u     // 1048576 : h [2048][512]
#define OFF_WFCT  1556480u    // 802816  : wfcT fp16 [512][3136] (k=c*49+pos)
#define OFF_C3    2359296u    // 3211264 : c3b fp16 [2048][3136]
#define OFF_C2    5570560u    // 5308416 : c2b fp16 [2048][9][9][64]
#define OFF_C1    10878976u   // c1b fp16 [CS][20][20][32]

// ---------------- weight prep ----------------
__global__ __launch_bounds__(256) void prep_kernel(
    const float* __restrict__ w1, const float* __restrict__ w2,
    const float* __restrict__ w3, half_t* __restrict__ w1p,
    half_t* __restrict__ w2T, half_t* __restrict__ w3T) {
  int g = blockIdx.x * 256 + threadIdx.x;   // 77824 total
  if (g < 8192) {
    // w1p[(tap*32+oc)*32+kk], kk = kx*3+c (<24) else 0 ; w1 is [oc][c][ky*8+kx]
    int kk = g & 31, oc = (g >> 5) & 31, tap = g >> 10;
    half_t v = (half_t)0.f;
    if (kk < 24) {
      int kx = kk / 3, c = kk - 3 * kx;
      v = (half_t)(w1[oc * 192 + c * 64 + tap * 8 + kx] * (1.0f / 255.0f));
    }
    w1p[g] = v;
    return;
  }
  int g2 = g - 8192;
  if (g2 < 32768) {                          // w2T[(tap*64+oc)*32+c]
    int c = g2 & 31, oc = (g2 >> 5) & 63, tap = g2 >> 11;
    w2T[g2] = (half_t)w2[oc * 512 + c * 16 + tap];
    return;
  }
  int g3 = g2 - 32768;
  if (g3 < 36864) {                          // w3T[(tap*64+oc)*64+c]
    int c = g3 & 63, oc = (g3 >> 6) & 63, tap = g3 >> 12;
    w3T[g3] = (half_t)w3[oc * 576 + c * 9 + tap];
  }
}

// ---- wfcT[n][k] = (half)wfc[k][n], k = c*49+pos : LDS-tiled transpose ----
__global__ __launch_bounds__(256) void prep_wfct(
    const float* __restrict__ wfc, half_t* __restrict__ wfcT) {
  __shared__ float t[32][33];
  int k0 = blockIdx.x * 32, n0 = blockIdx.y * 32;
  int tx = threadIdx.x & 31, ty = threadIdx.x >> 5;  // ty 0..7
#pragma unroll
  for (int i = 0; i < 4; ++i)
    t[ty + 8 * i][tx] = wfc[(size_t)(k0 + ty + 8 * i) * 512 + n0 + tx];
  __syncthreads();
#pragma unroll
  for (int i = 0; i < 4; ++i)
    wfcT[(size_t)(n0 + ty + 8 * i) * 3136 + k0 + tx] =
        (half_t)t[tx][ty + 8 * i];
}

// ---------------- conv1: one block per image, banded streaming ----------
// Input rows of band b: 16b..16b+19 (floats ib+4032b .. +5040). Outputs of
// band b: oy 4b..4b+3 = 80 rows = 5 M-tiles of 16. Lane (lc,q) of a tile:
// A row lp=tile*16+lc -> (oyl,ox); taps ky: 8 halfs at
// lds[(4*oyl+ky)*252 + 12*ox + q*8] (q==3 = K-pad zeros, weights also 0).
#define C1_BANDF 5040
#define C1_BANDV 1260
__global__ __launch_bounds__(256) void conv1_mfma(
    const float* __restrict__ img, const half_t* __restrict__ w1p,
    const float* __restrict__ b1, half_t* __restrict__ out, int n0) {
  __shared__ __align__(16) half_t As[2][C1_BANDF];
  int tid = threadIdx.x;
  int li = blockIdx.x;
  int w = tid >> 6, l = tid & 63, lc = l & 15, q = l >> 4;
  const float* ib = img + (size_t)(n0 + li) * 21168;
  half_t* ob = out + (size_t)li * 400 * 32;

  // B fragments in registers, once per block, reused for all 25 tiles
  half8 bfrag[8][2];
#pragma unroll
  for (int tap = 0; tap < 8; ++tap)
#pragma unroll
    for (int t = 0; t < 2; ++t)
      bfrag[tap][t] =
          *(const half8*)(w1p + (size_t)(tap * 32 + t * 16 + lc) * 32 + q * 8);
  float b1v[2] = {b1[lc], b1[16 + lc]};

  f32x4 fr[5];                                // staging registers
#define C1_LOADB(b)                                                   \
  {                                                                   \
    const float* src = ib + 4032 * (b);                               \
    _Pragma("unroll") for (int i = 0; i < 5; ++i) {                   \
      int g = tid + 256 * i;                                          \
      if (g < C1_BANDV) fr[i] = *(const f32x4*)(src + 4 * g);         \
    }                                                                 \
  }
#define C1_WRITEB(buf)                                                \
  {                                                                   \
    _Pragma("unroll") for (int i = 0; i < 5; ++i) {                   \
      int g = tid + 256 * i;                                          \
      if (g < C1_BANDV) {                                             \
        half4 o;                                                      \
        _Pragma("unroll") for (int j = 0; j < 4; ++j)                 \
            o[j] = (half_t)fr[i][j];                                  \
        *(half4*)&As[buf][4 * g] = o;                                 \
      }                                                               \
    }                                                                 \
  }

  C1_LOADB(0);
  C1_WRITEB(0);
  for (int b = 0; b < 5; ++b) {
    if (b < 4) C1_LOADB(b + 1);               // global loads span barrier+MFMA
    __syncthreads();                          // band b staged & visible
    int buf = b & 1;
    for (int tile = w; tile < 5; tile += 4) { // 5 tiles over 4 waves
      int lp = tile * 16 + lc;
      int oyl = lp / 20, ox = lp - oyl * 20;
      f32x4 acc[2];
      acc[0] = (f32x4){0.f, 0.f, 0.f, 0.f};
      acc[1] = (f32x4){0.f, 0.f, 0.f, 0.f};
#pragma unroll
      for (int ky = 0; ky < 8; ++ky) {
        half8 af;
        if (q < 3) {
          const half_t* p = &As[buf][(4 * oyl + ky) * 252 + 12 * ox + q * 8];
          *(half4*)&af = *(const half4*)p;          // 8B-aligned b64 reads
          *((half4*)&af + 1) = *((const half4*)(p + 4));
        } else {
#pragma unroll
          for (int j = 0; j < 8; ++j) af[j] = (half_t)0.f;
        }
        acc[0] = __builtin_amdgcn_mfma_f32_16x16x32_f16(af, bfrag[ky][0],
                                                        acc[0], 0, 0, 0);
        acc[1] = __builtin_amdgcn_mfma_f32_16x16x32_f16(af, bfrag[ky][1],
                                                        acc[1], 0, 0, 0);
      }
      // C: row=q*4+r (within tile), col=t*16+lc [m89]; out [m][32]
#pragma unroll
      for (int t = 0; t < 2; ++t) {
#pragma unroll
        for (int r = 0; r < 4; ++r) {
          int mr = b * 80 + tile * 16 + q * 4 + r;
          ob[(size_t)mr * 32 + t * 16 + lc] =
              (half_t)fmaxf(acc[t][r] + b1v[t], 0.f);
        }
      }
    }
    if (b < 4) C1_WRITEB((b + 1) & 1);        // other buffer; safe post-barrier
  }
}

// ---------------- conv2 implicit-GEMM MFMA: -> fp16 [li][9][9][64] ----------
// M-tile 64 x N=64, 4 waves, 16 taps x K=32. A row = in[li][2oy+ky][2ox+kx][:].
__global__ __launch_bounds__(256) void conv2_mfma(
    const half_t* __restrict__ in, const half_t* __restrict__ w2T,
    const float* __restrict__ b2, half_t* __restrict__ out) {
  __shared__ __align__(16) half_t As[64 * 40];
  __shared__ __align__(16) half_t Bs[64 * 40];
  int tid = threadIdx.x;
  int m0 = blockIdx.x * 64;
  int w = tid >> 6, l = tid & 63, lc = l & 15, q = l >> 4;
  int srow = tid >> 2, sseg = tid & 3;
  int m = m0 + srow;
  int li = m / 81, pos = m - li * 81;
  int oy = pos / 9, ox = pos - (pos / 9) * 9;
  const half_t* aBase = in + (size_t)((li * 20 + 2 * oy) * 20 + 2 * ox) * 32 + sseg * 8;
  const half_t* bBase = w2T + srow * 32 + sseg * 8;
  uint4 aReg = *(const uint4*)aBase;          // tap 0
  uint4 bReg = *(const uint4*)bBase;
  f32x4 acc[4];
#pragma unroll
  for (int t = 0; t < 4; ++t) acc[t] = (f32x4){0.f, 0.f, 0.f, 0.f};
#pragma unroll
  for (int tap = 0; tap < 16; ++tap) {
    __syncthreads();
    *(uint4*)&As[srow * 40 + sseg * 8] = aReg;
    *(uint4*)&Bs[srow * 40 + sseg * 8] = bReg;
    __syncthreads();
    if (tap < 15) {                           // prefetch next tap
      int nt = tap + 1, ky = nt >> 2, kx = nt & 3;
      aReg = *(const uint4*)(aBase + (ky * 20 + kx) * 32);
      bReg = *(const uint4*)(bBase + nt * 2048);
    }
    half8 af = *(const half8*)&As[(w * 16 + lc) * 40 + q * 8];
#pragma unroll
    for (int t = 0; t < 4; ++t) {
      half8 bf = *(const half8*)&Bs[(t * 16 + lc) * 40 + q * 8];
      acc[t] = __builtin_amdgcn_mfma_f32_16x16x32_f16(af, bf, acc[t], 0, 0, 0);
    }
  }
  // C: row=w*16+q*4+r, col=t*16+lc [m89]; out offset = m*64+col (layout [m][c])
#pragma unroll
  for (int t = 0; t < 4; ++t) {
#pragma unroll
    for (int r = 0; r < 4; ++r) {
      int mr = m0 + w * 16 + q * 4 + r;
      int col = t * 16 + lc;
      out[(size_t)mr * 64 + col] = (half_t)fmaxf(acc[t][r] + b2[col], 0.f);
    }
  }
}

// ---------------- conv3 implicit-GEMM MFMA: -> fp16 [li][c*49+pos] ----------
// M-tile 64 x N=64, 9 taps x 2 chunks x K=32. A row = in[li][oy+ky][ox+kx][:].
__global__ __launch_bounds__(256) void conv3_mfma(
    const half_t* __restrict__ in, const half_t* __restrict__ w3T,
    const float* __restrict__ b3, half_t* __restrict__ out) {
  __shared__ __align__(16) half_t As[64 * 40];
  __shared__ __align__(16) half_t Bs[64 * 40];
  int tid = threadIdx.x;
  int m0 = blockIdx.x * 64;
  int w = tid >> 6, l = tid & 63, lc = l & 15, q = l >> 4;
  int srow = tid >> 2, sseg = tid & 3;
  int m = m0 + srow;
  int li = m / 49, pos = m - li * 49;
  int oy = pos / 7, ox = pos - (pos / 7) * 7;
  const half_t* aBase = in + (size_t)((li * 9 + oy) * 9 + ox) * 64 + sseg * 8;
  const half_t* bBase = w3T + srow * 64 + sseg * 8;
  uint4 aReg = *(const uint4*)aBase;          // s=0: tap0 chunk0
  uint4 bReg = *(const uint4*)bBase;
  f32x4 acc[4];
#pragma unroll
  for (int t = 0; t < 4; ++t) acc[t] = (f32x4){0.f, 0.f, 0.f, 0.f};
#pragma unroll
  for (int s = 0; s < 18; ++s) {
    __syncthreads();
    *(uint4*)&As[srow * 40 + sseg * 8] = aReg;
    *(uint4*)&Bs[srow * 40 + sseg * 8] = bReg;
    __syncthreads();
    if (s < 17) {                             // prefetch next (tap,chunk)
      int ns = s + 1, tap = ns >> 1, ch = ns & 1;
      int ky = tap / 3, kx = tap - ky * 3;
      aReg = *(const uint4*)(aBase + ((ky * 9 + kx) * 64 + ch * 32));
      bReg = *(const uint4*)(bBase + (tap * 4096 + ch * 32));
    }
    half8 af = *(const half8*)&As[(w * 16 + lc) * 40 + q * 8];
#pragma unroll
    for (int t = 0; t < 4; ++t) {
      half8 bf = *(const half8*)&Bs[(t * 16 + lc) * 40 + q * 8];
      acc[t] = __builtin_amdgcn_mfma_f32_16x16x32_f16(af, bf, acc[t], 0, 0, 0);
    }
  }
  // write k-order c*49+pos (fc_mfma consumes this order; wfcT unchanged)
#pragma unroll
  for (int t = 0; t < 4; ++t) {
#pragma unroll
    for (int r = 0; r < 4; ++r) {
      int mr = m0 + w * 16 + q * 4 + r;
      int li2 = mr / 49, pos2 = mr - li2 * 49;
      int col = t * 16 + lc;
      out[(size_t)li2 * 3136 + col * 49 + pos2] =
          (half_t)fmaxf(acc[t][r] + b3[col], 0.f);
    }
  }
}

// ---------------- FC via MFMA: h = relu(A[2048,3136] @ wfc + bfc) -----------
// Unchanged from R6 (proven). A fp16 rows k=c*49+pos, Bt=wfcT fp16 [512][3136].
__global__ __launch_bounds__(256) void fc_mfma(
    const half_t* __restrict__ A, const half_t* __restrict__ Bt,
    const float* __restrict__ bias, float* __restrict__ C) {
  __shared__ __align__(16) half_t As[64 * 40];
  __shared__ __align__(16) half_t Bs[64 * 40];
  int tid = threadIdx.x;
  int m0 = blockIdx.y * 64, n0 = blockIdx.x * 64;
  int w = tid >> 6;
  int l = tid & 63;
  int lc = l & 15, q = l >> 4;
  int srow = tid >> 2, sseg = tid & 3;

  const half_t* aPtr = A + (size_t)(m0 + srow) * 3136 + sseg * 8;
  const half_t* bPtr = Bt + (size_t)(n0 + srow) * 3136 + sseg * 8;
  uint4 aReg = *(const uint4*)aPtr;
  uint4 bReg = *(const uint4*)bPtr;

  f32x4 acc[4];
#pragma unroll
  for (int t = 0; t < 4; ++t) acc[t] = (f32x4){0.f, 0.f, 0.f, 0.f};

  for (int k0 = 0; k0 < 3136; k0 += 32) {
    __syncthreads();
    *(uint4*)&As[srow * 40 + sseg * 8] = aReg;
    *(uint4*)&Bs[srow * 40 + sseg * 8] = bReg;
    __syncthreads();
    if (k0 + 32 < 3136) {                    // prefetch overlaps MFMA below
      aReg = *(const uint4*)(aPtr + k0 + 32);
      bReg = *(const uint4*)(bPtr + k0 + 32);
    }
    half8 af = *(const half8*)&As[(w * 16 + lc) * 40 + q * 8];
#pragma unroll
    for (int t = 0; t < 4; ++t) {
      half8 bf = *(const half8*)&Bs[(t * 16 + lc) * 40 + q * 8];
      acc[t] = __builtin_amdgcn_mfma_f32_16x16x32_f16(af, bf, acc[t], 0, 0, 0);
    }
  }
#pragma unroll
  for (int t = 0; t < 4; ++t) {
#pragma unroll
    for (int r = 0; r < 4; ++r) {
      int row = m0 + w * 16 + q * 4 + r;
      int col = n0 + t * 16 + lc;
      C[(size_t)row * 512 + col] = fmaxf(acc[t][r] + bias[col], 0.f);
    }
  }
}

// ---------------- wfeat = h @ Ww + bw : [2048,512]@[512,32] ----------------
__global__ __launch_bounds__(256) void wfeat_kernel(
    const float* __restrict__ h, const float* __restrict__ Ww,
    const float* __restrict__ bw, float* __restrict__ wf) {
  int g = blockIdx.x * 256 + threadIdx.x;   // 65536
  int row = g >> 5, oc = g & 31;
  float acc = bw[oc];
  const float* hr = h + (size_t)row * 512;
#pragma unroll 8
  for (int k = 0; k < 512; ++k) acc += hr[k] * Ww[k * 32 + oc];
  wf[g] = acc;
}

// ---------------- posfeat: one-hot MLP, one wave per row ----------------
__global__ __launch_bounds__(256) void posfeat_kernel(
    const int* __restrict__ pos, const float* __restrict__ wp1,
    const float* __restrict__ bp1, const float* __restrict__ wp2,
    const float* __restrict__ bp2, float* __restrict__ pf) {
  int row = (blockIdx.x * 256 + threadIdx.x) >> 6;  // 2048
  int l = threadIdx.x & 63;
  int p0 = pos[row * 2], p1 = pos[row * 2 + 1];
  float t1 = fmaxf(wp1[p0 * 64 + l] + wp1[(16 + p1) * 64 + l] + bp1[l], 0.f);
  float acc = bp2[l];
#pragma unroll
  for (int k = 0; k < 64; ++k) acc += __shfl(t1, k) * wp2[k * 64 + l];
  pf[row * 64 + l] = acc;
}

// ---------------- y0 = state0 @ [wpo1|wv1] : [64,8192]@[8192,128] ----------------
// R12: grid (b*32+kc), 256 thr = kh2 x n128; thread K=128; LDS pair-reduce;
// one atomicAdd per (block,n). 8 blocks/CU -> occupancy-bound no more.
__global__ __launch_bounds__(256) void y0_kernel(
    const float* __restrict__ s0, const float* __restrict__ wpo1,
    const float* __restrict__ wv1, float* __restrict__ y0) {
  __shared__ float red[128];
  int b = blockIdx.x >> 5, kc = blockIdx.x & 31;   // kc: 256-k chunk
  int n = threadIdx.x & 127, kh = threadIdx.x >> 7;
  const float* W = (n < 64) ? (wpo1 + n) : (wv1 + (n - 64));
  int k0 = kc * 256 + kh * 128;
  const float* s = s0 + (size_t)b * 8192 + k0;
  float acc = 0.f;
#pragma unroll 8
  for (int j = 0; j < 128; ++j) acc += s[j] * W[(size_t)(k0 + j) * 64];
  if (kh) red[n] = acc;
  __syncthreads();
  if (!kh) atomicAdd(y0 + b * 128 + n, acc + red[n]);
}

// ---------------- ystate: recurrence for hidden@W1 (cols 0..8191) ----------------
__global__ __launch_bounds__(128) void ystate_kernel(
    const float* __restrict__ y0, const float* __restrict__ done,
    const int* __restrict__ pos, const float* __restrict__ wf,
    const float* __restrict__ wpo1, const float* __restrict__ wv1,
    float* __restrict__ ys) {
  int b = blockIdx.x;
  int n = threadIdx.x;                      // 0..127
  const float* W = (n < 64) ? (wpo1 + n) : (wv1 + (n - 64));
  float y = y0[b * 128 + n];
  for (int t = 0; t < TT; ++t) {
    int row = t * BB + b;
    float mask = 1.f - done[row];
    int off = pos[row * 2] * 16 + pos[row * 2 + 1];
    y *= mask;
    const float* wfr = wf + row * 32;
#pragma unroll
    for (int c = 0; c < 32; ++c) y += wfr[c] * W[(size_t)(c * 256 + off) * 64];
    ys[(size_t)row * 128 + n] = y;
  }
}

// ---------------- final map state (output 2) ----------------
__global__ __launch_bounds__(256) void state_kernel(
    const float* __restrict__ s0, const float* __restrict__ done,
    const int* __restrict__ pos, const float* __restrict__ wf,
    float* __restrict__ out_state) {
  int b = blockIdx.x, tid = threadIdx.x;    // tid = spatial offset 0..255
  float s[32];
#pragma unroll
  for (int c = 0; c < 32; ++c) s[c] = s0[(size_t)b * 8192 + c * 256 + tid];
  for (int t = 0; t < TT; ++t) {
    int row = t * BB + b;
    float mask = 1.f - done[row];
    int off = pos[row * 2] * 16 + pos[row * 2 + 1];
#pragma unroll
    for (int c = 0; c < 32; ++c) s[c] *= mask;
    if (tid == off) {
#pragma unroll
      for (int c = 0; c < 32; ++c) s[c] += wf[row * 32 + c];
    }
  }
#pragma unroll
  for (int c = 0; c < 32; ++c) out_state[(size_t)b * 8192 + c * 256 + tid] = s[c];
}

// ---------------- heads: + pos-part of W1, ReLU, second layers ----------------
__global__ __launch_bounds__(256) void head_kernel(
    const float* __restrict__ ys, const float* __restrict__ pf,
    const float* __restrict__ wpo1, const float* __restrict__ wv1,
    const float* __restrict__ bpo1, const float* __restrict__ bv1,
    const float* __restrict__ wpo2, const float* __restrict__ bpo2,
    const float* __restrict__ wv2, const float* __restrict__ bv2,
    float* __restrict__ logits, float* __restrict__ vout) {
  int row = (blockIdx.x * 256 + threadIdx.x) >> 6;  // one wave per row
  int l = threadIdx.x & 63;
  float pfv = pf[row * 64 + l];
  float accp = bpo1[l] + ys[(size_t)row * 128 + l];
  float accv = bv1[l] + ys[(size_t)row * 128 + 64 + l];
#pragma unroll
  for (int k = 0; k < 64; ++k) {
    float pk = __shfl(pfv, k);
    accp += pk * wpo1[(size_t)(8192 + k) * 64 + l];
    accv += pk * wv1[(size_t)(8192 + k) * 64 + l];
  }
  float rp = fmaxf(accp, 0.f), rv = fmaxf(accv, 0.f);
#pragma unroll
  for (int a = 0; a < 5; ++a) {
    float pa = rp * wpo2[l * 5 + a];
#pragma unroll
    for (int m = 32; m >= 1; m >>= 1) pa += __shfl_xor(pa, m);
    if (l == 0) logits[row * 5 + a] = pa + bpo2[a];
  }
  float pv = rv * wv2[l];
#pragma unroll
  for (int m = 32; m >= 1; m >>= 1) pv += __shfl_xor(pv, m);
  if (l == 0) vout[row] = pv + bv2[0];
}

extern "C" void kernel_launch(void* const* d_in, const int* in_sizes, int n_in,
                              void* d_out, int out_size, void* d_ws, size_t ws_size,
                              hipStream_t stream) {
  const float* image = (const float*)d_in[0];
  const float* done = (const float*)d_in[1];
  const float* state0 = (const float*)d_in[2];
  const int* position = (const int*)d_in[3];
  const float* w1 = (const float*)d_in[4];
  const float* b1 = (const float*)d_in[5];
  const float* w2 = (const float*)d_in[6];
  const float* b2 = (const float*)d_in[7];
  const float* w3 = (const float*)d_in[8];
  const float* b3 = (const float*)d_in[9];
  const float* wfc = (const float*)d_in[10];
  const float* bfc = (const float*)d_in[11];
  const float* Ww = (const float*)d_in[12];
  const float* bw = (const float*)d_in[13];
  const float* wp1 = (const float*)d_in[14];
  const float* bp1 = (const float*)d_in[15];
  const float* wp2 = (const float*)d_in[16];
  const float* bp2 = (const float*)d_in[17];
  const float* wpo1 = (const float*)d_in[18];
  const float* bpo1 = (const float*)d_in[19];
  const float* wpo2 = (const float*)d_in[20];
  const float* bpo2 = (const float*)d_in[21];
  const float* wv1 = (const float*)d_in[22];
  const float* bv1 = (const float*)d_in[23];
  const float* wv2 = (const float*)d_in[24];
  const float* bv2 = (const float*)d_in[25];

  float* ws = (float*)d_ws;
  half_t* w1p = (half_t*)(ws + OFF_W1T);
  half_t* w2T = (half_t*)(ws + OFF_W2T);
  half_t* w3T = (half_t*)(ws + OFF_W3T);
  float* wf = ws + OFF_WF;
  float* pfb = ws + OFF_PF;
  float* y0 = ws + OFF_Y0;
  float* ysb = ws + OFF_YS;
  float* h = ws + OFF_H;
  half_t* wfcT = (half_t*)(ws + OFF_WFCT);
  half_t* c3b = (half_t*)(ws + OFF_C3);
  half_t* c2b = (half_t*)(ws + OFF_C2);
  half_t* c1b = (half_t*)(ws + OFF_C1);

  float* out = (float*)d_out;
  float* out_logits = out;            // [2048,5]
  float* out_v = out + 10240;         // [2048,1]
  float* out_state = out + 12288;     // [64,32,16,16]

  // Tier by ws_size (floats): A: CS=2048 no chunk, 95.9 MB;
  //                           B: CS=1024, 69.7 MB; C: CS=512, 56.6 MB.
  int CS;
  if (ws_size >= (size_t)23986176 * 4) CS = 2048;
  else if (ws_size >= (size_t)17432576 * 4) CS = 1024;
  else CS = 512;
  int nc = TBR / CS;

  hipMemsetAsync(y0, 0, 8192 * sizeof(float), stream);
  prep_kernel<<<304, 256, 0, stream>>>(w1, w2, w3, w1p, w2T, w3T);
  prep_wfct<<<dim3(98, 16), 256, 0, stream>>>(wfc, wfcT);

  for (int c = 0; c < nc; ++c) {
    int n0 = c * CS;
    conv1_mfma<<<CS, 256, 0, stream>>>(image, w1p, b1, c1b, n0);
    conv2_mfma<<<CS * 81 / 64, 256, 0, stream>>>(
        c1b, w2T, b2, c2b + (size_t)n0 * 5184);
  }
  conv3_mfma<<<TBR * 49 / 64, 256, 0, stream>>>(c2b, w3T, b3, c3b);
  fc_mfma<<<dim3(8, 32), 256, 0, stream>>>(c3b, wfcT, bfc, h);
  wfeat_kernel<<<256, 256, 0, stream>>>(h, Ww, bw, wf);
  posfeat_kernel<<<512, 256, 0, stream>>>(position, wp1, bp1, wp2, bp2, pfb);
  y0_kernel<<<2048, 256, 0, stream>>>(state0, wpo1, wv1, y0);
  ystate_kernel<<<64, 128, 0, stream>>>(y0, done, position, wf, wpo1, wv1, ysb);
  state_kernel<<<64, 256, 0, stream>>>(state0, done, position, wf, out_state);
  head_kernel<<<512, 256, 0, stream>>>(ysb, pfb, wpo1, wv1, bpo1, bv1,
                                       wpo2, bpo2, wv2, bv2, out_logits, out_v);
}

// Round 6
// 520.037 us; speedup vs baseline: 1.3412x; 1.0091x over previous
//
#include <hip/hip_runtime.h>
#include <hip/hip_bf16.h>

// MapAgent: NatureCNN (3 convs + FC) -> map-write scan -> policy/value heads.
// T=32, B=64, TB=2048.
//
// R13 change (theory: top-5 is now all harness-side workspace re-poison at
// 86% HBM peak -- our kernels are <100us each. The two with the known-bad
// "2 barriers per K-step" lockstep template are conv2 (32 barriers/block) and
// conv3 (36). That structure cost conv1 3x (R8->R11). Both inputs are tiny
// per image (25.6KB / 10.4KB)):
//  * conv2/conv3 -> one block per image: stage the WHOLE input in LDS once
//    (XOR-swizzled 16B slots: slot ^= (superrow&7)<<4, same formula on write
//    and read -> conflict-free pow-2 strides), ONE barrier, then all MFMAs
//    with B fragments in VGPRs (conv2: 2 n-tiles/wave; conv3: 1).
//    Tap summation order unchanged -> bit-identical math.
//  * Everything else unchanged.

#define TT 32
#define BB 64
#define TBR 2048

typedef _Float16 half_t;
typedef __attribute__((ext_vector_type(4))) _Float16 half4;
typedef __attribute__((ext_vector_type(8))) _Float16 half8;
typedef __attribute__((ext_vector_type(4))) float f32x4;

// ---- workspace offsets (floats) ----
#define OFF_W1T   0u          // 4096    : w1p fp16 [tap8][oc32][k32] zero-pad
#define OFF_W2T   6144u       // 16384   : w2T fp16 [tap16][oc64][c32]
#define OFF_W3T   22528u      // 18432   : w3T fp16 [tap9][oc64][c64]
#define OFF_WF    40960u      // 65536   : wfeat [2048][32]
#define OFF_PF    106496u     // 131072  : posfeat [2048][64]
#define OFF_Y0    237568u     // 8192    : y0 [64][128]
#define OFF_YS    245760u     // 262144  : ystate [2048][128]
#define OFF_H     507904u     // 1048576 : h [2048][512]
#define OFF_WFCT  1556480u    // 802816  : wfcT fp16 [512][3136] (k=c*49+pos)
#define OFF_C3    2359296u    // 3211264 : c3b fp16 [2048][3136]
#define OFF_C2    5570560u    // 5308416 : c2b fp16 [2048][9][9][64]
#define OFF_C1    10878976u   // c1b fp16 [CS][20][20][32]

// ---------------- weight prep ----------------
__global__ __launch_bounds__(256) void prep_kernel(
    const float* __restrict__ w1, const float* __restrict__ w2,
    const float* __restrict__ w3, half_t* __restrict__ w1p,
    half_t* __restrict__ w2T, half_t* __restrict__ w3T) {
  int g = blockIdx.x * 256 + threadIdx.x;   // 77824 total
  if (g < 8192) {
    // w1p[(tap*32+oc)*32+kk], kk = kx*3+c (<24) else 0 ; w1 is [oc][c][ky*8+kx]
    int kk = g & 31, oc = (g >> 5) & 31, tap = g >> 10;
    half_t v = (half_t)0.f;
    if (kk < 24) {
      int kx = kk / 3, c = kk - 3 * kx;
      v = (half_t)(w1[oc * 192 + c * 64 + tap * 8 + kx] * (1.0f / 255.0f));
    }
    w1p[g] = v;
    return;
  }
  int g2 = g - 8192;
  if (g2 < 32768) {                          // w2T[(tap*64+oc)*32+c]
    int c = g2 & 31, oc = (g2 >> 5) & 63, tap = g2 >> 11;
    w2T[g2] = (half_t)w2[oc * 512 + c * 16 + tap];
    return;
  }
  int g3 = g2 - 32768;
  if (g3 < 36864) {                          // w3T[(tap*64+oc)*64+c]
    int c = g3 & 63, oc = (g3 >> 6) & 63, tap = g3 >> 12;
    w3T[g3] = (half_t)w3[oc * 576 + c * 9 + tap];
  }
}

// ---- wfcT[n][k] = (half)wfc[k][n], k = c*49+pos : LDS-tiled transpose ----
__global__ __launch_bounds__(256) void prep_wfct(
    const float* __restrict__ wfc, half_t* __restrict__ wfcT) {
  __shared__ float t[32][33];
  int k0 = blockIdx.x * 32, n0 = blockIdx.y * 32;
  int tx = threadIdx.x & 31, ty = threadIdx.x >> 5;  // ty 0..7
#pragma unroll
  for (int i = 0; i < 4; ++i)
    t[ty + 8 * i][tx] = wfc[(size_t)(k0 + ty + 8 * i) * 512 + n0 + tx];
  __syncthreads();
#pragma unroll
  for (int i = 0; i < 4; ++i)
    wfcT[(size_t)(n0 + ty + 8 * i) * 3136 + k0 + tx] =
        (half_t)t[tx][ty + 8 * i];
}

// ---------------- conv1: one block per image, banded streaming ----------
#define C1_BANDF 5040
#define C1_BANDV 1260
__global__ __launch_bounds__(256) void conv1_mfma(
    const float* __restrict__ img, const half_t* __restrict__ w1p,
    const float* __restrict__ b1, half_t* __restrict__ out, int n0) {
  __shared__ __align__(16) half_t As[2][C1_BANDF];
  int tid = threadIdx.x;
  int li = blockIdx.x;
  int w = tid >> 6, l = tid & 63, lc = l & 15, q = l >> 4;
  const float* ib = img + (size_t)(n0 + li) * 21168;
  half_t* ob = out + (size_t)li * 400 * 32;

  // B fragments in registers, once per block, reused for all 25 tiles
  half8 bfrag[8][2];
#pragma unroll
  for (int tap = 0; tap < 8; ++tap)
#pragma unroll
    for (int t = 0; t < 2; ++t)
      bfrag[tap][t] =
          *(const half8*)(w1p + (size_t)(tap * 32 + t * 16 + lc) * 32 + q * 8);
  float b1v[2] = {b1[lc], b1[16 + lc]};

  f32x4 fr[5];                                // staging registers
#define C1_LOADB(b)                                                   \
  {                                                                   \
    const float* src = ib + 4032 * (b);                               \
    _Pragma("unroll") for (int i = 0; i < 5; ++i) {                   \
      int g = tid + 256 * i;                                          \
      if (g < C1_BANDV) fr[i] = *(const f32x4*)(src + 4 * g);         \
    }                                                                 \
  }
#define C1_WRITEB(buf)                                                \
  {                                                                   \
    _Pragma("unroll") for (int i = 0; i < 5; ++i) {                   \
      int g = tid + 256 * i;                                          \
      if (g < C1_BANDV) {                                             \
        half4 o;                                                      \
        _Pragma("unroll") for (int j = 0; j < 4; ++j)                 \
            o[j] = (half_t)fr[i][j];                                  \
        *(half4*)&As[buf][4 * g] = o;                                 \
      }                                                               \
    }                                                                 \
  }

  C1_LOADB(0);
  C1_WRITEB(0);
  for (int b = 0; b < 5; ++b) {
    if (b < 4) C1_LOADB(b + 1);               // global loads span barrier+MFMA
    __syncthreads();                          // band b staged & visible
    int buf = b & 1;
    for (int tile = w; tile < 5; tile += 4) { // 5 tiles over 4 waves
      int lp = tile * 16 + lc;
      int oyl = lp / 20, ox = lp - oyl * 20;
      f32x4 acc[2];
      acc[0] = (f32x4){0.f, 0.f, 0.f, 0.f};
      acc[1] = (f32x4){0.f, 0.f, 0.f, 0.f};
#pragma unroll
      for (int ky = 0; ky < 8; ++ky) {
        half8 af;
        if (q < 3) {
          const half_t* p = &As[buf][(4 * oyl + ky) * 252 + 12 * ox + q * 8];
          *(half4*)&af = *(const half4*)p;          // 8B-aligned b64 reads
          *((half4*)&af + 1) = *((const half4*)(p + 4));
        } else {
#pragma unroll
          for (int j = 0; j < 8; ++j) af[j] = (half_t)0.f;
        }
        acc[0] = __builtin_amdgcn_mfma_f32_16x16x32_f16(af, bfrag[ky][0],
                                                        acc[0], 0, 0, 0);
        acc[1] = __builtin_amdgcn_mfma_f32_16x16x32_f16(af, bfrag[ky][1],
                                                        acc[1], 0, 0, 0);
      }
      // C: row=q*4+r (within tile), col=t*16+lc [m89]; out [m][32]
#pragma unroll
      for (int t = 0; t < 2; ++t) {
#pragma unroll
        for (int r = 0; r < 4; ++r) {
          int mr = b * 80 + tile * 16 + q * 4 + r;
          ob[(size_t)mr * 32 + t * 16 + lc] =
              (half_t)fmaxf(acc[t][r] + b1v[t], 0.f);
        }
      }
    }
    if (b < 4) C1_WRITEB((b + 1) & 1);        // other buffer; safe post-barrier
  }
}

// ---------------- conv2: one block per image, full-input LDS ----------
// Input [20][20][32] fp16 = 25.6KB staged once with XOR-swizzle (128B
// super-row = 2 input pixels; slot ^= (sp&7)<<4). ONE barrier, then
// 6 M-tiles x 16 taps. Wave w: nt-pair (w&1), tiles {w>>1, +2, +4}.
// B (2 n-tiles = 32 oc) in 128 VGPRs from L2-hot w2T.
__global__ __launch_bounds__(256) void conv2_mfma(
    const half_t* __restrict__ in, const half_t* __restrict__ w2T,
    const float* __restrict__ b2, half_t* __restrict__ out, int n0) {
  __shared__ __align__(16) half_t As[12800];   // 25.6 KB
  int tid = threadIdx.x;
  int li = blockIdx.x;
  int w = tid >> 6, l = tid & 63, lc = l & 15, q = l >> 4;
  const half_t* inb = in + (size_t)li * 12800;

  // stage: 1600 16B chunks, swizzled
#pragma unroll
  for (int i = 0; i < 7; ++i) {
    int ci = tid + 256 * i;
    if (ci < 1600) {
      uint4 v = *(const uint4*)(inb + ci * 8);
      int ip = ci >> 2, sp = ip >> 1;
      int u = ((ip & 1) << 6) | ((ci & 3) << 4);
      int byte = sp * 128 + (u ^ ((sp & 7) << 4));
      *(uint4*)((char*)As + byte) = v;
    }
  }

  // B fragments: wave covers nt = (w&1)*2 + j, j=0..1
  half8 bfrag[16][2];
#pragma unroll
  for (int tap = 0; tap < 16; ++tap)
#pragma unroll
    for (int j = 0; j < 2; ++j) {
      int nt = (w & 1) * 2 + j;
      bfrag[tap][j] =
          *(const half8*)(w2T + (size_t)(tap * 64 + nt * 16 + lc) * 32 + q * 8);
    }
  float b2v[2];
#pragma unroll
  for (int j = 0; j < 2; ++j) b2v[j] = b2[(w & 1) * 32 + j * 16 + lc];

  __syncthreads();                              // the ONLY barrier

  half_t* ob = out + (size_t)(n0 + li) * 5184;  // [81][64]
#pragma unroll
  for (int ti = 0; ti < 3; ++ti) {
    int tile = (w >> 1) + 2 * ti;               // 0..5
    int row16 = tile * 16 + lc;
    int orow = row16 < 81 ? row16 : 80;         // clamp dead rows (masked store)
    int oy = orow / 9, ox = orow - oy * 9;
    f32x4 acc[2];
    acc[0] = (f32x4){0.f, 0.f, 0.f, 0.f};
    acc[1] = (f32x4){0.f, 0.f, 0.f, 0.f};
#pragma unroll
    for (int tap = 0; tap < 16; ++tap) {
      int ky = tap >> 2, kx = tap & 3;
      int ip = (2 * oy + ky) * 20 + 2 * ox + kx;
      int sp = ip >> 1;
      int u = ((ip & 1) << 6) | (q << 4);
      int byte = sp * 128 + (u ^ ((sp & 7) << 4));
      half8 af = *(const half8*)((const char*)As + byte);
      acc[0] = __builtin_amdgcn_mfma_f32_16x16x32_f16(af, bfrag[tap][0],
                                                      acc[0], 0, 0, 0);
      acc[1] = __builtin_amdgcn_mfma_f32_16x16x32_f16(af, bfrag[tap][1],
                                                      acc[1], 0, 0, 0);
    }
    // C: row=tile*16+q*4+r, col=(w&1)*32+j*16+lc [m89]
#pragma unroll
    for (int j = 0; j < 2; ++j) {
#pragma unroll
      for (int r = 0; r < 4; ++r) {
        int mr = tile * 16 + q * 4 + r;
        if (mr < 81) {
          int col = (w & 1) * 32 + j * 16 + lc;
          ob[(size_t)mr * 64 + col] = (half_t)fmaxf(acc[j][r] + b2v[j], 0.f);
        }
      }
    }
  }
}

// ---------------- conv3: one block per image, full-input LDS ----------
// Input [9][9][64] fp16 = 10.4KB staged once (swizzle on 128B rows).
// ONE barrier; wave w owns n-tile w; 4 M-tiles x 9 taps x 2 ch.
// Tap/ch order matches old s-loop -> identical summation order.
__global__ __launch_bounds__(256) void conv3_mfma(
    const half_t* __restrict__ in, const half_t* __restrict__ w3T,
    const float* __restrict__ b3, half_t* __restrict__ out) {
  __shared__ __align__(16) half_t As[5184];    // 10.4 KB
  int tid = threadIdx.x;
  int li = blockIdx.x;
  int w = tid >> 6, l = tid & 63, lc = l & 15, q = l >> 4;
  const half_t* inb = in + (size_t)li * 5184;

  // stage: 648 16B chunks, swizzled (row = 128B)
#pragma unroll
  for (int i = 0; i < 3; ++i) {
    int ci = tid + 256 * i;
    if (ci < 648) {
      uint4 v = *(const uint4*)(inb + ci * 8);
      int ir = ci >> 3, cc = ci & 7;
      int byte = ir * 128 + (((cc << 4)) ^ ((ir & 7) << 4));
      *(uint4*)((char*)As + byte) = v;
    }
  }

  // B fragments: wave owns nt = w (16 oc)
  half8 bfrag[9][2];
#pragma unroll
  for (int tap = 0; tap < 9; ++tap)
#pragma unroll
    for (int ch = 0; ch < 2; ++ch)
      bfrag[tap][ch] = *(const half8*)(
          w3T + (size_t)(tap * 64 + w * 16 + lc) * 64 + ch * 32 + q * 8);
  float b3v = b3[w * 16 + lc];

  __syncthreads();                              // the ONLY barrier

  half_t* ob = out + (size_t)li * 3136;         // k-order c*49+pos
#pragma unroll
  for (int tile = 0; tile < 4; ++tile) {
    int row16 = tile * 16 + lc;
    int orow = row16 < 49 ? row16 : 48;         // clamp dead rows
    int oy = orow / 7, ox = orow - oy * 7;
    f32x4 acc = (f32x4){0.f, 0.f, 0.f, 0.f};
#pragma unroll
    for (int tap = 0; tap < 9; ++tap) {
      int ky = tap / 3, kx = tap - ky * 3;
      int ir = (oy + ky) * 9 + ox + kx;
#pragma unroll
      for (int ch = 0; ch < 2; ++ch) {
        int byte = ir * 128 + (((ch << 6) | (q << 4)) ^ ((ir & 7) << 4));
        half8 af = *(const half8*)((const char*)As + byte);
        acc = __builtin_amdgcn_mfma_f32_16x16x32_f16(af, bfrag[tap][ch],
                                                     acc, 0, 0, 0);
      }
    }
    // C: pos=tile*16+q*4+r, col=w*16+lc; write out[col*49+pos]
#pragma unroll
    for (int r = 0; r < 4; ++r) {
      int pos = tile * 16 + q * 4 + r;
      if (pos < 49) {
        int col = w * 16 + lc;
        ob[(size_t)col * 49 + pos] = (half_t)fmaxf(acc[r] + b3v, 0.f);
      }
    }
  }
}

// ---------------- FC via MFMA: h = relu(A[2048,3136] @ wfc + bfc) -----------
// Unchanged from R6 (proven). A fp16 rows k=c*49+pos, Bt=wfcT fp16 [512][3136].
__global__ __launch_bounds__(256) void fc_mfma(
    const half_t* __restrict__ A, const half_t* __restrict__ Bt,
    const float* __restrict__ bias, float* __restrict__ C) {
  __shared__ __align__(16) half_t As[64 * 40];
  __shared__ __align__(16) half_t Bs[64 * 40];
  int tid = threadIdx.x;
  int m0 = blockIdx.y * 64, n0 = blockIdx.x * 64;
  int w = tid >> 6;
  int l = tid & 63;
  int lc = l & 15, q = l >> 4;
  int srow = tid >> 2, sseg = tid & 3;

  const half_t* aPtr = A + (size_t)(m0 + srow) * 3136 + sseg * 8;
  const half_t* bPtr = Bt + (size_t)(n0 + srow) * 3136 + sseg * 8;
  uint4 aReg = *(const uint4*)aPtr;
  uint4 bReg = *(const uint4*)bPtr;

  f32x4 acc[4];
#pragma unroll
  for (int t = 0; t < 4; ++t) acc[t] = (f32x4){0.f, 0.f, 0.f, 0.f};

  for (int k0 = 0; k0 < 3136; k0 += 32) {
    __syncthreads();
    *(uint4*)&As[srow * 40 + sseg * 8] = aReg;
    *(uint4*)&Bs[srow * 40 + sseg * 8] = bReg;
    __syncthreads();
    if (k0 + 32 < 3136) {                    // prefetch overlaps MFMA below
      aReg = *(const uint4*)(aPtr + k0 + 32);
      bReg = *(const uint4*)(bPtr + k0 + 32);
    }
    half8 af = *(const half8*)&As[(w * 16 + lc) * 40 + q * 8];
#pragma unroll
    for (int t = 0; t < 4; ++t) {
      half8 bf = *(const half8*)&Bs[(t * 16 + lc) * 40 + q * 8];
      acc[t] = __builtin_amdgcn_mfma_f32_16x16x32_f16(af, bf, acc[t], 0, 0, 0);
    }
  }
#pragma unroll
  for (int t = 0; t < 4; ++t) {
#pragma unroll
    for (int r = 0; r < 4; ++r) {
      int row = m0 + w * 16 + q * 4 + r;
      int col = n0 + t * 16 + lc;
      C[(size_t)row * 512 + col] = fmaxf(acc[t][r] + bias[col], 0.f);
    }
  }
}

// ---------------- wfeat = h @ Ww + bw : [2048,512]@[512,32] ----------------
__global__ __launch_bounds__(256) void wfeat_kernel(
    const float* __restrict__ h, const float* __restrict__ Ww,
    const float* __restrict__ bw, float* __restrict__ wf) {
  int g = blockIdx.x * 256 + threadIdx.x;   // 65536
  int row = g >> 5, oc = g & 31;
  float acc = bw[oc];
  const float* hr = h + (size_t)row * 512;
#pragma unroll 8
  for (int k = 0; k < 512; ++k) acc += hr[k] * Ww[k * 32 + oc];
  wf[g] = acc;
}

// ---------------- posfeat: one-hot MLP, one wave per row ----------------
__global__ __launch_bounds__(256) void posfeat_kernel(
    const int* __restrict__ pos, const float* __restrict__ wp1,
    const float* __restrict__ bp1, const float* __restrict__ wp2,
    const float* __restrict__ bp2, float* __restrict__ pf) {
  int row = (blockIdx.x * 256 + threadIdx.x) >> 6;  // 2048
  int l = threadIdx.x & 63;
  int p0 = pos[row * 2], p1 = pos[row * 2 + 1];
  float t1 = fmaxf(wp1[p0 * 64 + l] + wp1[(16 + p1) * 64 + l] + bp1[l], 0.f);
  float acc = bp2[l];
#pragma unroll
  for (int k = 0; k < 64; ++k) acc += __shfl(t1, k) * wp2[k * 64 + l];
  pf[row * 64 + l] = acc;
}

// ---------------- y0 = state0 @ [wpo1|wv1] : [64,8192]@[8192,128] ----------------
// R12: grid (b*32+kc), 256 thr = kh2 x n128; thread K=128; LDS pair-reduce;
// one atomicAdd per (block,n). 8 blocks/CU -> occupancy-bound no more.
__global__ __launch_bounds__(256) void y0_kernel(
    const float* __restrict__ s0, const float* __restrict__ wpo1,
    const float* __restrict__ wv1, float* __restrict__ y0) {
  __shared__ float red[128];
  int b = blockIdx.x >> 5, kc = blockIdx.x & 31;   // kc: 256-k chunk
  int n = threadIdx.x & 127, kh = threadIdx.x >> 7;
  const float* W = (n < 64) ? (wpo1 + n) : (wv1 + (n - 64));
  int k0 = kc * 256 + kh * 128;
  const float* s = s0 + (size_t)b * 8192 + k0;
  float acc = 0.f;
#pragma unroll 8
  for (int j = 0; j < 128; ++j) acc += s[j] * W[(size_t)(k0 + j) * 64];
  if (kh) red[n] = acc;
  __syncthreads();
  if (!kh) atomicAdd(y0 + b * 128 + n, acc + red[n]);
}

// ---------------- ystate: recurrence for hidden@W1 (cols 0..8191) ----------------
__global__ __launch_bounds__(128) void ystate_kernel(
    const float* __restrict__ y0, const float* __restrict__ done,
    const int* __restrict__ pos, const float* __restrict__ wf,
    const float* __restrict__ wpo1, const float* __restrict__ wv1,
    float* __restrict__ ys) {
  int b = blockIdx.x;
  int n = threadIdx.x;                      // 0..127
  const float* W = (n < 64) ? (wpo1 + n) : (wv1 + (n - 64));
  float y = y0[b * 128 + n];
  for (int t = 0; t < TT; ++t) {
    int row = t * BB + b;
    float mask = 1.f - done[row];
    int off = pos[row * 2] * 16 + pos[row * 2 + 1];
    y *= mask;
    const float* wfr = wf + row * 32;
#pragma unroll
    for (int c = 0; c < 32; ++c) y += wfr[c] * W[(size_t)(c * 256 + off) * 64];
    ys[(size_t)row * 128 + n] = y;
  }
}

// ---------------- final map state (output 2) ----------------
__global__ __launch_bounds__(256) void state_kernel(
    const float* __restrict__ s0, const float* __restrict__ done,
    const int* __restrict__ pos, const float* __restrict__ wf,
    float* __restrict__ out_state) {
  int b = blockIdx.x, tid = threadIdx.x;    // tid = spatial offset 0..255
  float s[32];
#pragma unroll
  for (int c = 0; c < 32; ++c) s[c] = s0[(size_t)b * 8192 + c * 256 + tid];
  for (int t = 0; t < TT; ++t) {
    int row = t * BB + b;
    float mask = 1.f - done[row];
    int off = pos[row * 2] * 16 + pos[row * 2 + 1];
#pragma unroll
    for (int c = 0; c < 32; ++c) s[c] *= mask;
    if (tid == off) {
#pragma unroll
      for (int c = 0; c < 32; ++c) s[c] += wf[row * 32 + c];
    }
  }
#pragma unroll
  for (int c = 0; c < 32; ++c) out_state[(size_t)b * 8192 + c * 256 + tid] = s[c];
}

// ---------------- heads: + pos-part of W1, ReLU, second layers ----------------
__global__ __launch_bounds__(256) void head_kernel(
    const float* __restrict__ ys, const float* __restrict__ pf,
    const float* __restrict__ wpo1, const float* __restrict__ wv1,
    const float* __restrict__ bpo1, const float* __restrict__ bv1,
    const float* __restrict__ wpo2, const float* __restrict__ bpo2,
    const float* __restrict__ wv2, const float* __restrict__ bv2,
    float* __restrict__ logits, float* __restrict__ vout) {
  int row = (blockIdx.x * 256 + threadIdx.x) >> 6;  // one wave per row
  int l = threadIdx.x & 63;
  float pfv = pf[row * 64 + l];
  float accp = bpo1[l] + ys[(size_t)row * 128 + l];
  float accv = bv1[l] + ys[(size_t)row * 128 + 64 + l];
#pragma unroll
  for (int k = 0; k < 64; ++k) {
    float pk = __shfl(pfv, k);
    accp += pk * wpo1[(size_t)(8192 + k) * 64 + l];
    accv += pk * wv1[(size_t)(8192 + k) * 64 + l];
  }
  float rp = fmaxf(accp, 0.f), rv = fmaxf(accv, 0.f);
#pragma unroll
  for (int a = 0; a < 5; ++a) {
    float pa = rp * wpo2[l * 5 + a];
#pragma unroll
    for (int m = 32; m >= 1; m >>= 1) pa += __shfl_xor(pa, m);
    if (l == 0) logits[row * 5 + a] = pa + bpo2[a];
  }
  float pv = rv * wv2[l];
#pragma unroll
  for (int m = 32; m >= 1; m >>= 1) pv += __shfl_xor(pv, m);
  if (l == 0) vout[row] = pv + bv2[0];
}

extern "C" void kernel_launch(void* const* d_in, const int* in_sizes, int n_in,
                              void* d_out, int out_size, void* d_ws, size_t ws_size,
                              hipStream_t stream) {
  const float* image = (const float*)d_in[0];
  const float* done = (const float*)d_in[1];
  const float* state0 = (const float*)d_in[2];
  const int* position = (const int*)d_in[3];
  const float* w1 = (const float*)d_in[4];
  const float* b1 = (const float*)d_in[5];
  const float* w2 = (const float*)d_in[6];
  const float* b2 = (const float*)d_in[7];
  const float* w3 = (const float*)d_in[8];
  const float* b3 = (const float*)d_in[9];
  const float* wfc = (const float*)d_in[10];
  const float* bfc = (const float*)d_in[11];
  const float* Ww = (const float*)d_in[12];
  const float* bw = (const float*)d_in[13];
  const float* wp1 = (const float*)d_in[14];
  const float* bp1 = (const float*)d_in[15];
  const float* wp2 = (const float*)d_in[16];
  const float* bp2 = (const float*)d_in[17];
  const float* wpo1 = (const float*)d_in[18];
  const float* bpo1 = (const float*)d_in[19];
  const float* wpo2 = (const float*)d_in[20];
  const float* bpo2 = (const float*)d_in[21];
  const float* wv1 = (const float*)d_in[22];
  const float* bv1 = (const float*)d_in[23];
  const float* wv2 = (const float*)d_in[24];
  const float* bv2 = (const float*)d_in[25];

  float* ws = (float*)d_ws;
  half_t* w1p = (half_t*)(ws + OFF_W1T);
  half_t* w2T = (half_t*)(ws + OFF_W2T);
  half_t* w3T = (half_t*)(ws + OFF_W3T);
  float* wf = ws + OFF_WF;
  float* pfb = ws + OFF_PF;
  float* y0 = ws + OFF_Y0;
  float* ysb = ws + OFF_YS;
  float* h = ws + OFF_H;
  half_t* wfcT = (half_t*)(ws + OFF_WFCT);
  half_t* c3b = (half_t*)(ws + OFF_C3);
  half_t* c2b = (half_t*)(ws + OFF_C2);
  half_t* c1b = (half_t*)(ws + OFF_C1);

  float* out = (float*)d_out;
  float* out_logits = out;            // [2048,5]
  float* out_v = out + 10240;         // [2048,1]
  float* out_state = out + 12288;     // [64,32,16,16]

  // Tier by ws_size (floats): A: CS=2048 no chunk, 95.9 MB;
  //                           B: CS=1024, 69.7 MB; C: CS=512, 56.6 MB.
  int CS;
  if (ws_size >= (size_t)23986176 * 4) CS = 2048;
  else if (ws_size >= (size_t)17432576 * 4) CS = 1024;
  else CS = 512;
  int nc = TBR / CS;

  hipMemsetAsync(y0, 0, 8192 * sizeof(float), stream);
  prep_kernel<<<304, 256, 0, stream>>>(w1, w2, w3, w1p, w2T, w3T);
  prep_wfct<<<dim3(98, 16), 256, 0, stream>>>(wfc, wfcT);

  for (int c = 0; c < nc; ++c) {
    int n0 = c * CS;
    conv1_mfma<<<CS, 256, 0, stream>>>(image, w1p, b1, c1b, n0);
    conv2_mfma<<<CS, 256, 0, stream>>>(c1b, w2T, b2, c2b, n0);
  }
  conv3_mfma<<<TBR, 256, 0, stream>>>(c2b, w3T, b3, c3b);
  fc_mfma<<<dim3(8, 32), 256, 0, stream>>>(c3b, wfcT, bfc, h);
  wfeat_kernel<<<256, 256, 0, stream>>>(h, Ww, bw, wf);
  posfeat_kernel<<<512, 256, 0, stream>>>(position, wp1, bp1, wp2, bp2, pfb);
  y0_kernel<<<2048, 256, 0, stream>>>(state0, wpo1, wv1, y0);
  ystate_kernel<<<64, 128, 0, stream>>>(y0, done, position, wf, wpo1, wv1, ysb);
  state_kernel<<<64, 256, 0, stream>>>(state0, done, position, wf, out_state);
  head_kernel<<<512, 256, 0, stream>>>(ysb, pfb, wpo1, wv1, bpo1, bv1,
                                       wpo2, bpo2, wv2, bv2, out_logits, out_v);
}

// Round 7
// 452.821 us; speedup vs baseline: 1.5403x; 1.1484x over previous
//
#include <hip/hip_runtime.h>
#include <hip/hip_bf16.h>

// MapAgent: NatureCNN (3 convs + FC) -> map-write scan -> policy/value heads.
// T=32, B=64, TB=2048.
//
// R14 changes (theory: top-5 is harness ws-poison (86% HBM, roofline); ours
// are each <100us. Gap vs ~220us bottom-up floor sits in the serial tail:
// 6 back-to-back small launches, ystate at 64 blocks = 1/4 block/CU with a
// 32-step serial chain of 32 scattered L2 gathers each):
//  * ystate -> delta (parallel gather-GEMM, 1024 blocks, coalesced) + scan
//    (y = y*mask + delta; 32 FMAs, loads prefetchable). FP32 reassoc only.
//  * launch merges: {prep,prep_wfct}->prep_all; {wfeat,posfeat,y0}->mid1;
//    {delta,state}->mid2. 13 -> 10 dispatches, each grid fills the machine.
//  * conv1/conv2/conv3/fc/head unchanged.

#define TT 32
#define BB 64
#define TBR 2048

typedef _Float16 half_t;
typedef __attribute__((ext_vector_type(4))) _Float16 half4;
typedef __attribute__((ext_vector_type(8))) _Float16 half8;
typedef __attribute__((ext_vector_type(4))) float f32x4;

// ---- workspace offsets (floats) ----
#define OFF_W1T   0u          // 4096    : w1p fp16 [tap8][oc32][k32] zero-pad
#define OFF_W2T   6144u       // 16384   : w2T fp16 [tap16][oc64][c32]
#define OFF_W3T   22528u      // 18432   : w3T fp16 [tap9][oc64][c64]
#define OFF_WF    40960u      // 65536   : wfeat [2048][32]
#define OFF_PF    106496u     // 131072  : posfeat [2048][64]
#define OFF_Y0    237568u     // 8192    : y0 [64][128]
#define OFF_YS    245760u     // 262144  : ystate [2048][128]
#define OFF_H     507904u     // 1048576 : h [2048][512]
#define OFF_DELTA 1556480u    // 262144  : delta [2048][128]
#define OFF_WFCT  1818624u    // 802816  : wfcT fp16 [512][3136] (k=c*49+pos)
#define OFF_C3    2621440u    // 3211264 : c3b fp16 [2048][3136]
#define OFF_C2    5832704u    // 5308416 : c2b fp16 [2048][9][9][64]
#define OFF_C1    11141120u   // c1b fp16 [CS][20][20][32]

// ---------------- merged weight prep (prep + wfcT transpose) ----------------
__global__ __launch_bounds__(256) void prep_all(
    const float* __restrict__ w1, const float* __restrict__ w2,
    const float* __restrict__ w3, half_t* __restrict__ w1p,
    half_t* __restrict__ w2T, half_t* __restrict__ w3T,
    const float* __restrict__ wfc, half_t* __restrict__ wfcT) {
  __shared__ float t[32][33];
  int bx = blockIdx.x;
  if (bx < 304) {
    int g = bx * 256 + threadIdx.x;   // 77824 total
    if (g < 8192) {
      // w1p[(tap*32+oc)*32+kk], kk=kx*3+c (<24) else 0 ; w1 is [oc][c][ky*8+kx]
      int kk = g & 31, oc = (g >> 5) & 31, tap = g >> 10;
      half_t v = (half_t)0.f;
      if (kk < 24) {
        int kx = kk / 3, c = kk - 3 * kx;
        v = (half_t)(w1[oc * 192 + c * 64 + tap * 8 + kx] * (1.0f / 255.0f));
      }
      w1p[g] = v;
      return;
    }
    int g2 = g - 8192;
    if (g2 < 32768) {                          // w2T[(tap*64+oc)*32+c]
      int c = g2 & 31, oc = (g2 >> 5) & 63, tap = g2 >> 11;
      w2T[g2] = (half_t)w2[oc * 512 + c * 16 + tap];
      return;
    }
    int g3 = g2 - 32768;
    if (g3 < 36864) {                          // w3T[(tap*64+oc)*64+c]
      int c = g3 & 63, oc = (g3 >> 6) & 63, tap = g3 >> 12;
      w3T[g3] = (half_t)w3[oc * 576 + c * 9 + tap];
    }
    return;
  }
  // wfcT[n][k] = (half)wfc[k][n], k = c*49+pos : LDS-tiled transpose
  int gb = bx - 304;                           // 0..1567
  int k0 = (gb % 98) * 32, n0 = (gb / 98) * 32;
  int tx = threadIdx.x & 31, ty = threadIdx.x >> 5;  // ty 0..7
#pragma unroll
  for (int i = 0; i < 4; ++i)
    t[ty + 8 * i][tx] = wfc[(size_t)(k0 + ty + 8 * i) * 512 + n0 + tx];
  __syncthreads();
#pragma unroll
  for (int i = 0; i < 4; ++i)
    wfcT[(size_t)(n0 + ty + 8 * i) * 3136 + k0 + tx] =
        (half_t)t[tx][ty + 8 * i];
}

// ---------------- conv1: one block per image, banded streaming ----------
#define C1_BANDF 5040
#define C1_BANDV 1260
__global__ __launch_bounds__(256) void conv1_mfma(
    const float* __restrict__ img, const half_t* __restrict__ w1p,
    const float* __restrict__ b1, half_t* __restrict__ out, int n0) {
  __shared__ __align__(16) half_t As[2][C1_BANDF];
  int tid = threadIdx.x;
  int li = blockIdx.x;
  int w = tid >> 6, l = tid & 63, lc = l & 15, q = l >> 4;
  const float* ib = img + (size_t)(n0 + li) * 21168;
  half_t* ob = out + (size_t)li * 400 * 32;

  // B fragments in registers, once per block, reused for all 25 tiles
  half8 bfrag[8][2];
#pragma unroll
  for (int tap = 0; tap < 8; ++tap)
#pragma unroll
    for (int t = 0; t < 2; ++t)
      bfrag[tap][t] =
          *(const half8*)(w1p + (size_t)(tap * 32 + t * 16 + lc) * 32 + q * 8);
  float b1v[2] = {b1[lc], b1[16 + lc]};

  f32x4 fr[5];                                // staging registers
#define C1_LOADB(b)                                                   \
  {                                                                   \
    const float* src = ib + 4032 * (b);                               \
    _Pragma("unroll") for (int i = 0; i < 5; ++i) {                   \
      int g = tid + 256 * i;                                          \
      if (g < C1_BANDV) fr[i] = *(const f32x4*)(src + 4 * g);         \
    }                                                                 \
  }
#define C1_WRITEB(buf)                                                \
  {                                                                   \
    _Pragma("unroll") for (int i = 0; i < 5; ++i) {                   \
      int g = tid + 256 * i;                                          \
      if (g < C1_BANDV) {                                             \
        half4 o;                                                      \
        _Pragma("unroll") for (int j = 0; j < 4; ++j)                 \
            o[j] = (half_t)fr[i][j];                                  \
        *(half4*)&As[buf][4 * g] = o;                                 \
      }                                                               \
    }                                                                 \
  }

  C1_LOADB(0);
  C1_WRITEB(0);
  for (int b = 0; b < 5; ++b) {
    if (b < 4) C1_LOADB(b + 1);               // global loads span barrier+MFMA
    __syncthreads();                          // band b staged & visible
    int buf = b & 1;
    for (int tile = w; tile < 5; tile += 4) { // 5 tiles over 4 waves
      int lp = tile * 16 + lc;
      int oyl = lp / 20, ox = lp - oyl * 20;
      f32x4 acc[2];
      acc[0] = (f32x4){0.f, 0.f, 0.f, 0.f};
      acc[1] = (f32x4){0.f, 0.f, 0.f, 0.f};
#pragma unroll
      for (int ky = 0; ky < 8; ++ky) {
        half8 af;
        if (q < 3) {
          const half_t* p = &As[buf][(4 * oyl + ky) * 252 + 12 * ox + q * 8];
          *(half4*)&af = *(const half4*)p;          // 8B-aligned b64 reads
          *((half4*)&af + 1) = *((const half4*)(p + 4));
        } else {
#pragma unroll
          for (int j = 0; j < 8; ++j) af[j] = (half_t)0.f;
        }
        acc[0] = __builtin_amdgcn_mfma_f32_16x16x32_f16(af, bfrag[ky][0],
                                                        acc[0], 0, 0, 0);
        acc[1] = __builtin_amdgcn_mfma_f32_16x16x32_f16(af, bfrag[ky][1],
                                                        acc[1], 0, 0, 0);
      }
      // C: row=q*4+r (within tile), col=t*16+lc [m89]; out [m][32]
#pragma unroll
      for (int t = 0; t < 2; ++t) {
#pragma unroll
        for (int r = 0; r < 4; ++r) {
          int mr = b * 80 + tile * 16 + q * 4 + r;
          ob[(size_t)mr * 32 + t * 16 + lc] =
              (half_t)fmaxf(acc[t][r] + b1v[t], 0.f);
        }
      }
    }
    if (b < 4) C1_WRITEB((b + 1) & 1);        // other buffer; safe post-barrier
  }
}

// ---------------- conv2: one block per image, full-input LDS ----------
__global__ __launch_bounds__(256) void conv2_mfma(
    const half_t* __restrict__ in, const half_t* __restrict__ w2T,
    const float* __restrict__ b2, half_t* __restrict__ out, int n0) {
  __shared__ __align__(16) half_t As[12800];   // 25.6 KB
  int tid = threadIdx.x;
  int li = blockIdx.x;
  int w = tid >> 6, l = tid & 63, lc = l & 15, q = l >> 4;
  const half_t* inb = in + (size_t)li * 12800;

  // stage: 1600 16B chunks, swizzled
#pragma unroll
  for (int i = 0; i < 7; ++i) {
    int ci = tid + 256 * i;
    if (ci < 1600) {
      uint4 v = *(const uint4*)(inb + ci * 8);
      int ip = ci >> 2, sp = ip >> 1;
      int u = ((ip & 1) << 6) | ((ci & 3) << 4);
      int byte = sp * 128 + (u ^ ((sp & 7) << 4));
      *(uint4*)((char*)As + byte) = v;
    }
  }

  // B fragments: wave covers nt = (w&1)*2 + j, j=0..1
  half8 bfrag[16][2];
#pragma unroll
  for (int tap = 0; tap < 16; ++tap)
#pragma unroll
    for (int j = 0; j < 2; ++j) {
      int nt = (w & 1) * 2 + j;
      bfrag[tap][j] =
          *(const half8*)(w2T + (size_t)(tap * 64 + nt * 16 + lc) * 32 + q * 8);
    }
  float b2v[2];
#pragma unroll
  for (int j = 0; j < 2; ++j) b2v[j] = b2[(w & 1) * 32 + j * 16 + lc];

  __syncthreads();                              // the ONLY barrier

  half_t* ob = out + (size_t)(n0 + li) * 5184;  // [81][64]
#pragma unroll
  for (int ti = 0; ti < 3; ++ti) {
    int tile = (w >> 1) + 2 * ti;               // 0..5
    int row16 = tile * 16 + lc;
    int orow = row16 < 81 ? row16 : 80;         // clamp dead rows (masked store)
    int oy = orow / 9, ox = orow - oy * 9;
    f32x4 acc[2];
    acc[0] = (f32x4){0.f, 0.f, 0.f, 0.f};
    acc[1] = (f32x4){0.f, 0.f, 0.f, 0.f};
#pragma unroll
    for (int tap = 0; tap < 16; ++tap) {
      int ky = tap >> 2, kx = tap & 3;
      int ip = (2 * oy + ky) * 20 + 2 * ox + kx;
      int sp = ip >> 1;
      int u = ((ip & 1) << 6) | (q << 4);
      int byte = sp * 128 + (u ^ ((sp & 7) << 4));
      half8 af = *(const half8*)((const char*)As + byte);
      acc[0] = __builtin_amdgcn_mfma_f32_16x16x32_f16(af, bfrag[tap][0],
                                                      acc[0], 0, 0, 0);
      acc[1] = __builtin_amdgcn_mfma_f32_16x16x32_f16(af, bfrag[tap][1],
                                                      acc[1], 0, 0, 0);
    }
    // C: row=tile*16+q*4+r, col=(w&1)*32+j*16+lc [m89]
#pragma unroll
    for (int j = 0; j < 2; ++j) {
#pragma unroll
      for (int r = 0; r < 4; ++r) {
        int mr = tile * 16 + q * 4 + r;
        if (mr < 81) {
          int col = (w & 1) * 32 + j * 16 + lc;
          ob[(size_t)mr * 64 + col] = (half_t)fmaxf(acc[j][r] + b2v[j], 0.f);
        }
      }
    }
  }
}

// ---------------- conv3: one block per image, full-input LDS ----------
__global__ __launch_bounds__(256) void conv3_mfma(
    const half_t* __restrict__ in, const half_t* __restrict__ w3T,
    const float* __restrict__ b3, half_t* __restrict__ out) {
  __shared__ __align__(16) half_t As[5184];    // 10.4 KB
  int tid = threadIdx.x;
  int li = blockIdx.x;
  int w = tid >> 6, l = tid & 63, lc = l & 15, q = l >> 4;
  const half_t* inb = in + (size_t)li * 5184;

  // stage: 648 16B chunks, swizzled (row = 128B)
#pragma unroll
  for (int i = 0; i < 3; ++i) {
    int ci = tid + 256 * i;
    if (ci < 648) {
      uint4 v = *(const uint4*)(inb + ci * 8);
      int ir = ci >> 3, cc = ci & 7;
      int byte = ir * 128 + (((cc << 4)) ^ ((ir & 7) << 4));
      *(uint4*)((char*)As + byte) = v;
    }
  }

  // B fragments: wave owns nt = w (16 oc)
  half8 bfrag[9][2];
#pragma unroll
  for (int tap = 0; tap < 9; ++tap)
#pragma unroll
    for (int ch = 0; ch < 2; ++ch)
      bfrag[tap][ch] = *(const half8*)(
          w3T + (size_t)(tap * 64 + w * 16 + lc) * 64 + ch * 32 + q * 8);
  float b3v = b3[w * 16 + lc];

  __syncthreads();                              // the ONLY barrier

  half_t* ob = out + (size_t)li * 3136;         // k-order c*49+pos
#pragma unroll
  for (int tile = 0; tile < 4; ++tile) {
    int row16 = tile * 16 + lc;
    int orow = row16 < 49 ? row16 : 48;         // clamp dead rows
    int oy = orow / 7, ox = orow - oy * 7;
    f32x4 acc = (f32x4){0.f, 0.f, 0.f, 0.f};
#pragma unroll
    for (int tap = 0; tap < 9; ++tap) {
      int ky = tap / 3, kx = tap - ky * 3;
      int ir = (oy + ky) * 9 + ox + kx;
#pragma unroll
      for (int ch = 0; ch < 2; ++ch) {
        int byte = ir * 128 + (((ch << 6) | (q << 4)) ^ ((ir & 7) << 4));
        half8 af = *(const half8*)((const char*)As + byte);
        acc = __builtin_amdgcn_mfma_f32_16x16x32_f16(af, bfrag[tap][ch],
                                                     acc, 0, 0, 0);
      }
    }
    // C: pos=tile*16+q*4+r, col=w*16+lc; write out[col*49+pos]
#pragma unroll
    for (int r = 0; r < 4; ++r) {
      int pos = tile * 16 + q * 4 + r;
      if (pos < 49) {
        int col = w * 16 + lc;
        ob[(size_t)col * 49 + pos] = (half_t)fmaxf(acc[r] + b3v, 0.f);
      }
    }
  }
}

// ---------------- FC via MFMA: h = relu(A[2048,3136] @ wfc + bfc) -----------
__global__ __launch_bounds__(256) void fc_mfma(
    const half_t* __restrict__ A, const half_t* __restrict__ Bt,
    const float* __restrict__ bias, float* __restrict__ C) {
  __shared__ __align__(16) half_t As[64 * 40];
  __shared__ __align__(16) half_t Bs[64 * 40];
  int tid = threadIdx.x;
  int m0 = blockIdx.y * 64, n0 = blockIdx.x * 64;
  int w = tid >> 6;
  int l = tid & 63;
  int lc = l & 15, q = l >> 4;
  int srow = tid >> 2, sseg = tid & 3;

  const half_t* aPtr = A + (size_t)(m0 + srow) * 3136 + sseg * 8;
  const half_t* bPtr = Bt + (size_t)(n0 + srow) * 3136 + sseg * 8;
  uint4 aReg = *(const uint4*)aPtr;
  uint4 bReg = *(const uint4*)bPtr;

  f32x4 acc[4];
#pragma unroll
  for (int t = 0; t < 4; ++t) acc[t] = (f32x4){0.f, 0.f, 0.f, 0.f};

  for (int k0 = 0; k0 < 3136; k0 += 32) {
    __syncthreads();
    *(uint4*)&As[srow * 40 + sseg * 8] = aReg;
    *(uint4*)&Bs[srow * 40 + sseg * 8] = bReg;
    __syncthreads();
    if (k0 + 32 < 3136) {                    // prefetch overlaps MFMA below
      aReg = *(const uint4*)(aPtr + k0 + 32);
      bReg = *(const uint4*)(bPtr + k0 + 32);
    }
    half8 af = *(const half8*)&As[(w * 16 + lc) * 40 + q * 8];
#pragma unroll
    for (int t = 0; t < 4; ++t) {
      half8 bf = *(const half8*)&Bs[(t * 16 + lc) * 40 + q * 8];
      acc[t] = __builtin_amdgcn_mfma_f32_16x16x32_f16(af, bf, acc[t], 0, 0, 0);
    }
  }
#pragma unroll
  for (int t = 0; t < 4; ++t) {
#pragma unroll
    for (int r = 0; r < 4; ++r) {
      int row = m0 + w * 16 + q * 4 + r;
      int col = n0 + t * 16 + lc;
      C[(size_t)row * 512 + col] = fmaxf(acc[t][r] + bias[col], 0.f);
    }
  }
}

// ---------------- mid1: wfeat + posfeat + y0 (independent; one launch) ------
__global__ __launch_bounds__(256) void mid1_kernel(
    const float* __restrict__ h, const float* __restrict__ Ww,
    const float* __restrict__ bw, float* __restrict__ wf,
    const int* __restrict__ pos, const float* __restrict__ wp1,
    const float* __restrict__ bp1, const float* __restrict__ wp2,
    const float* __restrict__ bp2, float* __restrict__ pf,
    const float* __restrict__ s0, const float* __restrict__ wpo1,
    const float* __restrict__ wv1, float* __restrict__ y0) {
  __shared__ float red[128];
  int bx = blockIdx.x;
  if (bx < 256) {
    // ---- wfeat = h @ Ww + bw : [2048,512]@[512,32] ----
    int g = bx * 256 + threadIdx.x;
    int row = g >> 5, oc = g & 31;
    float acc = bw[oc];
    const float* hr = h + (size_t)row * 512;
#pragma unroll 8
    for (int k = 0; k < 512; ++k) acc += hr[k] * Ww[k * 32 + oc];
    wf[g] = acc;
    return;
  }
  if (bx < 768) {
    // ---- posfeat: one-hot MLP, one wave per row ----
    int row = ((bx - 256) * 256 + threadIdx.x) >> 6;  // 2048
    int l = threadIdx.x & 63;
    int p0 = pos[row * 2], p1 = pos[row * 2 + 1];
    float t1 = fmaxf(wp1[p0 * 64 + l] + wp1[(16 + p1) * 64 + l] + bp1[l], 0.f);
    float acc = bp2[l];
#pragma unroll
    for (int k = 0; k < 64; ++k) acc += __shfl(t1, k) * wp2[k * 64 + l];
    pf[row * 64 + l] = acc;
    return;
  }
  // ---- y0 = state0 @ [wpo1|wv1] : grid (b*32+kc), thread (kh2 x n128) ----
  int g = bx - 768;                                // 0..2047
  int b = g >> 5, kc = g & 31;                     // kc: 256-k chunk
  int n = threadIdx.x & 127, kh = threadIdx.x >> 7;
  const float* W = (n < 64) ? (wpo1 + n) : (wv1 + (n - 64));
  int k0 = kc * 256 + kh * 128;
  const float* s = s0 + (size_t)b * 8192 + k0;
  float acc = 0.f;
#pragma unroll 8
  for (int j = 0; j < 128; ++j) acc += s[j] * W[(size_t)(k0 + j) * 64];
  if (kh) red[n] = acc;
  __syncthreads();
  if (!kh) atomicAdd(y0 + b * 128 + n, acc + red[n]);
}

// ---------------- mid2: delta (parallel recurrence input) + final state -----
// delta[row][n] = sum_c wf[row][c] * W_n[(c*256+off_row)*64]  (coalesced 512B)
__global__ __launch_bounds__(256) void mid2_kernel(
    const int* __restrict__ pos, const float* __restrict__ wf,
    const float* __restrict__ wpo1, const float* __restrict__ wv1,
    float* __restrict__ delta, const float* __restrict__ s0,
    const float* __restrict__ done, float* __restrict__ out_state) {
  int bx = blockIdx.x;
  if (bx < 1024) {
    // ---- delta: 2 rows per block ----
    int row = bx * 2 + (threadIdx.x >> 7);
    int n = threadIdx.x & 127;
    const float* W = (n < 64) ? (wpo1 + n) : (wv1 + (n - 64));
    int off = pos[row * 2] * 16 + pos[row * 2 + 1];
    const float* wfr = wf + row * 32;
    float d = 0.f;
#pragma unroll
    for (int c = 0; c < 32; ++c) d += wfr[c] * W[(size_t)(c * 256 + off) * 64];
    delta[(size_t)row * 128 + n] = d;
    return;
  }
  // ---- final map state (output 2) ----
  int b = bx - 1024, tid = threadIdx.x;       // tid = spatial offset 0..255
  float s[32];
#pragma unroll
  for (int c = 0; c < 32; ++c) s[c] = s0[(size_t)b * 8192 + c * 256 + tid];
  for (int t = 0; t < TT; ++t) {
    int row = t * BB + b;
    float mask = 1.f - done[row];
    int off = pos[row * 2] * 16 + pos[row * 2 + 1];
#pragma unroll
    for (int c = 0; c < 32; ++c) s[c] *= mask;
    if (tid == off) {
#pragma unroll
      for (int c = 0; c < 32; ++c) s[c] += wf[row * 32 + c];
    }
  }
#pragma unroll
  for (int c = 0; c < 32; ++c) out_state[(size_t)b * 8192 + c * 256 + tid] = s[c];
}

// ---------------- scan: y = y*mask + delta (trivial recurrence) -------------
__global__ __launch_bounds__(128) void scan_kernel(
    const float* __restrict__ y0, const float* __restrict__ done,
    const float* __restrict__ delta, float* __restrict__ ys) {
  int b = blockIdx.x;
  int n = threadIdx.x;                      // 0..127
  float y = y0[b * 128 + n];
  for (int t = 0; t < TT; ++t) {
    int row = t * BB + b;
    y = y * (1.f - done[row]) + delta[(size_t)row * 128 + n];
    ys[(size_t)row * 128 + n] = y;
  }
}

// ---------------- heads: + pos-part of W1, ReLU, second layers ----------------
__global__ __launch_bounds__(256) void head_kernel(
    const float* __restrict__ ys, const float* __restrict__ pf,
    const float* __restrict__ wpo1, const float* __restrict__ wv1,
    const float* __restrict__ bpo1, const float* __restrict__ bv1,
    const float* __restrict__ wpo2, const float* __restrict__ bpo2,
    const float* __restrict__ wv2, const float* __restrict__ bv2,
    float* __restrict__ logits, float* __restrict__ vout) {
  int row = (blockIdx.x * 256 + threadIdx.x) >> 6;  // one wave per row
  int l = threadIdx.x & 63;
  float pfv = pf[row * 64 + l];
  float accp = bpo1[l] + ys[(size_t)row * 128 + l];
  float accv = bv1[l] + ys[(size_t)row * 128 + 64 + l];
#pragma unroll
  for (int k = 0; k < 64; ++k) {
    float pk = __shfl(pfv, k);
    accp += pk * wpo1[(size_t)(8192 + k) * 64 + l];
    accv += pk * wv1[(size_t)(8192 + k) * 64 + l];
  }
  float rp = fmaxf(accp, 0.f), rv = fmaxf(accv, 0.f);
#pragma unroll
  for (int a = 0; a < 5; ++a) {
    float pa = rp * wpo2[l * 5 + a];
#pragma unroll
    for (int m = 32; m >= 1; m >>= 1) pa += __shfl_xor(pa, m);
    if (l == 0) logits[row * 5 + a] = pa + bpo2[a];
  }
  float pv = rv * wv2[l];
#pragma unroll
  for (int m = 32; m >= 1; m >>= 1) pv += __shfl_xor(pv, m);
  if (l == 0) vout[row] = pv + bv2[0];
}

extern "C" void kernel_launch(void* const* d_in, const int* in_sizes, int n_in,
                              void* d_out, int out_size, void* d_ws, size_t ws_size,
                              hipStream_t stream) {
  const float* image = (const float*)d_in[0];
  const float* done = (const float*)d_in[1];
  const float* state0 = (const float*)d_in[2];
  const int* position = (const int*)d_in[3];
  const float* w1 = (const float*)d_in[4];
  const float* b1 = (const float*)d_in[5];
  const float* w2 = (const float*)d_in[6];
  const float* b2 = (const float*)d_in[7];
  const float* w3 = (const float*)d_in[8];
  const float* b3 = (const float*)d_in[9];
  const float* wfc = (const float*)d_in[10];
  const float* bfc = (const float*)d_in[11];
  const float* Ww = (const float*)d_in[12];
  const float* bw = (const float*)d_in[13];
  const float* wp1 = (const float*)d_in[14];
  const float* bp1 = (const float*)d_in[15];
  const float* wp2 = (const float*)d_in[16];
  const float* bp2 = (const float*)d_in[17];
  const float* wpo1 = (const float*)d_in[18];
  const float* bpo1 = (const float*)d_in[19];
  const float* wpo2 = (const float*)d_in[20];
  const float* bpo2 = (const float*)d_in[21];
  const float* wv1 = (const float*)d_in[22];
  const float* bv1 = (const float*)d_in[23];
  const float* wv2 = (const float*)d_in[24];
  const float* bv2 = (const float*)d_in[25];

  float* ws = (float*)d_ws;
  half_t* w1p = (half_t*)(ws + OFF_W1T);
  half_t* w2T = (half_t*)(ws + OFF_W2T);
  half_t* w3T = (half_t*)(ws + OFF_W3T);
  float* wf = ws + OFF_WF;
  float* pfb = ws + OFF_PF;
  float* y0 = ws + OFF_Y0;
  float* ysb = ws + OFF_YS;
  float* h = ws + OFF_H;
  float* deltab = ws + OFF_DELTA;
  half_t* wfcT = (half_t*)(ws + OFF_WFCT);
  half_t* c3b = (half_t*)(ws + OFF_C3);
  half_t* c2b = (half_t*)(ws + OFF_C2);
  half_t* c1b = (half_t*)(ws + OFF_C1);

  float* out = (float*)d_out;
  float* out_logits = out;            // [2048,5]
  float* out_v = out + 10240;         // [2048,1]
  float* out_state = out + 12288;     // [64,32,16,16]

  // Tier by ws_size (floats): A: CS=2048 no chunk, 97.0 MB;
  //                           B: CS=1024, 70.8 MB; C: CS=512, 57.7 MB.
  int CS;
  if (ws_size >= (size_t)24248320 * 4) CS = 2048;
  else if (ws_size >= (size_t)17694720 * 4) CS = 1024;
  else CS = 512;
  int nc = TBR / CS;

  hipMemsetAsync(y0, 0, 8192 * sizeof(float), stream);
  prep_all<<<1872, 256, 0, stream>>>(w1, w2, w3, w1p, w2T, w3T, wfc, wfcT);

  for (int c = 0; c < nc; ++c) {
    int n0 = c * CS;
    conv1_mfma<<<CS, 256, 0, stream>>>(image, w1p, b1, c1b, n0);
    conv2_mfma<<<CS, 256, 0, stream>>>(c1b, w2T, b2, c2b, n0);
  }
  conv3_mfma<<<TBR, 256, 0, stream>>>(c2b, w3T, b3, c3b);
  fc_mfma<<<dim3(8, 32), 256, 0, stream>>>(c3b, wfcT, bfc, h);
  mid1_kernel<<<2816, 256, 0, stream>>>(h, Ww, bw, wf, position, wp1, bp1,
                                        wp2, bp2, pfb, state0, wpo1, wv1, y0);
  mid2_kernel<<<1088, 256, 0, stream>>>(position, wf, wpo1, wv1, deltab,
                                        state0, done, out_state);
  scan_kernel<<<64, 128, 0, stream>>>(y0, done, deltab, ysb);
  head_kernel<<<512, 256, 0, stream>>>(ysb, pfb, wpo1, wv1, bpo1, bv1,
                                       wpo2, bpo2, wv2, bv2, out_logits, out_v);
}

// Round 8
// 450.251 us; speedup vs baseline: 1.5491x; 1.0057x over previous
//
#include <hip/hip_runtime.h>
#include <hip/hip_bf16.h>

// MapAgent: NatureCNN (3 convs + FC) -> map-write scan -> policy/value heads.
// T=32, B=64, TB=2048.
//
// R15 change (theory: fc_mfma is the last R8-style lockstep kernel: 98
// K-steps x 2 barriers at 256 blocks = 1 block/CU -- the exact combo that
// made y0/conv1 slow. Floor ~10us, est 30-50us):
//  * fc: K-split 2x -> grid (8,32,2)=512 blocks (2/CU; barrier stalls overlap
//    across blocks) + double-buffered LDS -> ONE barrier per K-step. Writes
//    raw fp32 partials h0/h1 (no bias/relu); h1 reuses dead c2b space.
//  * bias+relu folded into mid1's wfeat (sole consumer of h):
//    acc += relu(h0[k]+h1[k]+bfc[k]) * Ww. FP32 reassoc at one K-boundary.
//  * Everything else unchanged from R14.

#define TT 32
#define BB 64
#define TBR 2048

typedef _Float16 half_t;
typedef __attribute__((ext_vector_type(4))) _Float16 half4;
typedef __attribute__((ext_vector_type(8))) _Float16 half8;
typedef __attribute__((ext_vector_type(4))) float f32x4;

// ---- workspace offsets (floats) ----
#define OFF_W1T   0u          // 4096    : w1p fp16 [tap8][oc32][k32] zero-pad
#define OFF_W2T   6144u       // 16384   : w2T fp16 [tap16][oc64][c32]
#define OFF_W3T   22528u      // 18432   : w3T fp16 [tap9][oc64][c64]
#define OFF_WF    40960u      // 65536   : wfeat [2048][32]
#define OFF_PF    106496u     // 131072  : posfeat [2048][64]
#define OFF_Y0    237568u     // 8192    : y0 [64][128]
#define OFF_YS    245760u     // 262144  : ystate [2048][128]
#define OFF_H     507904u     // 1048576 : h0 [2048][512] raw K-half partial
#define OFF_DELTA 1556480u    // 262144  : delta [2048][128]
#define OFF_WFCT  1818624u    // 802816  : wfcT fp16 [512][3136] (k=c*49+pos)
#define OFF_C3    2621440u    // 3211264 : c3b fp16 [2048][3136]
#define OFF_C2    5832704u    // 5308416 : c2b fp16 [2048][9][9][64]; dead
                              //           after conv3 -> h1 reuses this space
#define OFF_C1    11141120u   // c1b fp16 [CS][20][20][32]

// ---------------- merged weight prep (prep + wfcT transpose) ----------------
__global__ __launch_bounds__(256) void prep_all(
    const float* __restrict__ w1, const float* __restrict__ w2,
    const float* __restrict__ w3, half_t* __restrict__ w1p,
    half_t* __restrict__ w2T, half_t* __restrict__ w3T,
    const float* __restrict__ wfc, half_t* __restrict__ wfcT) {
  __shared__ float t[32][33];
  int bx = blockIdx.x;
  if (bx < 304) {
    int g = bx * 256 + threadIdx.x;   // 77824 total
    if (g < 8192) {
      // w1p[(tap*32+oc)*32+kk], kk=kx*3+c (<24) else 0 ; w1 is [oc][c][ky*8+kx]
      int kk = g & 31, oc = (g >> 5) & 31, tap = g >> 10;
      half_t v = (half_t)0.f;
      if (kk < 24) {
        int kx = kk / 3, c = kk - 3 * kx;
        v = (half_t)(w1[oc * 192 + c * 64 + tap * 8 + kx] * (1.0f / 255.0f));
      }
      w1p[g] = v;
      return;
    }
    int g2 = g - 8192;
    if (g2 < 32768) {                          // w2T[(tap*64+oc)*32+c]
      int c = g2 & 31, oc = (g2 >> 5) & 63, tap = g2 >> 11;
      w2T[g2] = (half_t)w2[oc * 512 + c * 16 + tap];
      return;
    }
    int g3 = g2 - 32768;
    if (g3 < 36864) {                          // w3T[(tap*64+oc)*64+c]
      int c = g3 & 63, oc = (g3 >> 6) & 63, tap = g3 >> 12;
      w3T[g3] = (half_t)w3[oc * 576 + c * 9 + tap];
    }
    return;
  }
  // wfcT[n][k] = (half)wfc[k][n], k = c*49+pos : LDS-tiled transpose
  int gb = bx - 304;                           // 0..1567
  int k0 = (gb % 98) * 32, n0 = (gb / 98) * 32;
  int tx = threadIdx.x & 31, ty = threadIdx.x >> 5;  // ty 0..7
#pragma unroll
  for (int i = 0; i < 4; ++i)
    t[ty + 8 * i][tx] = wfc[(size_t)(k0 + ty + 8 * i) * 512 + n0 + tx];
  __syncthreads();
#pragma unroll
  for (int i = 0; i < 4; ++i)
    wfcT[(size_t)(n0 + ty + 8 * i) * 3136 + k0 + tx] =
        (half_t)t[tx][ty + 8 * i];
}

// ---------------- conv1: one block per image, banded streaming ----------
#define C1_BANDF 5040
#define C1_BANDV 1260
__global__ __launch_bounds__(256) void conv1_mfma(
    const float* __restrict__ img, const half_t* __restrict__ w1p,
    const float* __restrict__ b1, half_t* __restrict__ out, int n0) {
  __shared__ __align__(16) half_t As[2][C1_BANDF];
  int tid = threadIdx.x;
  int li = blockIdx.x;
  int w = tid >> 6, l = tid & 63, lc = l & 15, q = l >> 4;
  const float* ib = img + (size_t)(n0 + li) * 21168;
  half_t* ob = out + (size_t)li * 400 * 32;

  // B fragments in registers, once per block, reused for all 25 tiles
  half8 bfrag[8][2];
#pragma unroll
  for (int tap = 0; tap < 8; ++tap)
#pragma unroll
    for (int t = 0; t < 2; ++t)
      bfrag[tap][t] =
          *(const half8*)(w1p + (size_t)(tap * 32 + t * 16 + lc) * 32 + q * 8);
  float b1v[2] = {b1[lc], b1[16 + lc]};

  f32x4 fr[5];                                // staging registers
#define C1_LOADB(b)                                                   \
  {                                                                   \
    const float* src = ib + 4032 * (b);                               \
    _Pragma("unroll") for (int i = 0; i < 5; ++i) {                   \
      int g = tid + 256 * i;                                          \
      if (g < C1_BANDV) fr[i] = *(const f32x4*)(src + 4 * g);         \
    }                                                                 \
  }
#define C1_WRITEB(buf)                                                \
  {                                                                   \
    _Pragma("unroll") for (int i = 0; i < 5; ++i) {                   \
      int g = tid + 256 * i;                                          \
      if (g < C1_BANDV) {                                             \
        half4 o;                                                      \
        _Pragma("unroll") for (int j = 0; j < 4; ++j)                 \
            o[j] = (half_t)fr[i][j];                                  \
        *(half4*)&As[buf][4 * g] = o;                                 \
      }                                                               \
    }                                                                 \
  }

  C1_LOADB(0);
  C1_WRITEB(0);
  for (int b = 0; b < 5; ++b) {
    if (b < 4) C1_LOADB(b + 1);               // global loads span barrier+MFMA
    __syncthreads();                          // band b staged & visible
    int buf = b & 1;
    for (int tile = w; tile < 5; tile += 4) { // 5 tiles over 4 waves
      int lp = tile * 16 + lc;
      int oyl = lp / 20, ox = lp - oyl * 20;
      f32x4 acc[2];
      acc[0] = (f32x4){0.f, 0.f, 0.f, 0.f};
      acc[1] = (f32x4){0.f, 0.f, 0.f, 0.f};
#pragma unroll
      for (int ky = 0; ky < 8; ++ky) {
        half8 af;
        if (q < 3) {
          const half_t* p = &As[buf][(4 * oyl + ky) * 252 + 12 * ox + q * 8];
          *(half4*)&af = *(const half4*)p;          // 8B-aligned b64 reads
          *((half4*)&af + 1) = *((const half4*)(p + 4));
        } else {
#pragma unroll
          for (int j = 0; j < 8; ++j) af[j] = (half_t)0.f;
        }
        acc[0] = __builtin_amdgcn_mfma_f32_16x16x32_f16(af, bfrag[ky][0],
                                                        acc[0], 0, 0, 0);
        acc[1] = __builtin_amdgcn_mfma_f32_16x16x32_f16(af, bfrag[ky][1],
                                                        acc[1], 0, 0, 0);
      }
      // C: row=q*4+r (within tile), col=t*16+lc [m89]; out [m][32]
#pragma unroll
      for (int t = 0; t < 2; ++t) {
#pragma unroll
        for (int r = 0; r < 4; ++r) {
          int mr = b * 80 + tile * 16 + q * 4 + r;
          ob[(size_t)mr * 32 + t * 16 + lc] =
              (half_t)fmaxf(acc[t][r] + b1v[t], 0.f);
        }
      }
    }
    if (b < 4) C1_WRITEB((b + 1) & 1);        // other buffer; safe post-barrier
  }
}

// ---------------- conv2: one block per image, full-input LDS ----------
__global__ __launch_bounds__(256) void conv2_mfma(
    const half_t* __restrict__ in, const half_t* __restrict__ w2T,
    const float* __restrict__ b2, half_t* __restrict__ out, int n0) {
  __shared__ __align__(16) half_t As[12800];   // 25.6 KB
  int tid = threadIdx.x;
  int li = blockIdx.x;
  int w = tid >> 6, l = tid & 63, lc = l & 15, q = l >> 4;
  const half_t* inb = in + (size_t)li * 12800;

  // stage: 1600 16B chunks, swizzled
#pragma unroll
  for (int i = 0; i < 7; ++i) {
    int ci = tid + 256 * i;
    if (ci < 1600) {
      uint4 v = *(const uint4*)(inb + ci * 8);
      int ip = ci >> 2, sp = ip >> 1;
      int u = ((ip & 1) << 6) | ((ci & 3) << 4);
      int byte = sp * 128 + (u ^ ((sp & 7) << 4));
      *(uint4*)((char*)As + byte) = v;
    }
  }

  // B fragments: wave covers nt = (w&1)*2 + j, j=0..1
  half8 bfrag[16][2];
#pragma unroll
  for (int tap = 0; tap < 16; ++tap)
#pragma unroll
    for (int j = 0; j < 2; ++j) {
      int nt = (w & 1) * 2 + j;
      bfrag[tap][j] =
          *(const half8*)(w2T + (size_t)(tap * 64 + nt * 16 + lc) * 32 + q * 8);
    }
  float b2v[2];
#pragma unroll
  for (int j = 0; j < 2; ++j) b2v[j] = b2[(w & 1) * 32 + j * 16 + lc];

  __syncthreads();                              // the ONLY barrier

  half_t* ob = out + (size_t)(n0 + li) * 5184;  // [81][64]
#pragma unroll
  for (int ti = 0; ti < 3; ++ti) {
    int tile = (w >> 1) + 2 * ti;               // 0..5
    int row16 = tile * 16 + lc;
    int orow = row16 < 81 ? row16 : 80;         // clamp dead rows (masked store)
    int oy = orow / 9, ox = orow - oy * 9;
    f32x4 acc[2];
    acc[0] = (f32x4){0.f, 0.f, 0.f, 0.f};
    acc[1] = (f32x4){0.f, 0.f, 0.f, 0.f};
#pragma unroll
    for (int tap = 0; tap < 16; ++tap) {
      int ky = tap >> 2, kx = tap & 3;
      int ip = (2 * oy + ky) * 20 + 2 * ox + kx;
      int sp = ip >> 1;
      int u = ((ip & 1) << 6) | (q << 4);
      int byte = sp * 128 + (u ^ ((sp & 7) << 4));
      half8 af = *(const half8*)((const char*)As + byte);
      acc[0] = __builtin_amdgcn_mfma_f32_16x16x32_f16(af, bfrag[tap][0],
                                                      acc[0], 0, 0, 0);
      acc[1] = __builtin_amdgcn_mfma_f32_16x16x32_f16(af, bfrag[tap][1],
                                                      acc[1], 0, 0, 0);
    }
    // C: row=tile*16+q*4+r, col=(w&1)*32+j*16+lc [m89]
#pragma unroll
    for (int j = 0; j < 2; ++j) {
#pragma unroll
      for (int r = 0; r < 4; ++r) {
        int mr = tile * 16 + q * 4 + r;
        if (mr < 81) {
          int col = (w & 1) * 32 + j * 16 + lc;
          ob[(size_t)mr * 64 + col] = (half_t)fmaxf(acc[j][r] + b2v[j], 0.f);
        }
      }
    }
  }
}

// ---------------- conv3: one block per image, full-input LDS ----------
__global__ __launch_bounds__(256) void conv3_mfma(
    const half_t* __restrict__ in, const half_t* __restrict__ w3T,
    const float* __restrict__ b3, half_t* __restrict__ out) {
  __shared__ __align__(16) half_t As[5184];    // 10.4 KB
  int tid = threadIdx.x;
  int li = blockIdx.x;
  int w = tid >> 6, l = tid & 63, lc = l & 15, q = l >> 4;
  const half_t* inb = in + (size_t)li * 5184;

  // stage: 648 16B chunks, swizzled (row = 128B)
#pragma unroll
  for (int i = 0; i < 3; ++i) {
    int ci = tid + 256 * i;
    if (ci < 648) {
      uint4 v = *(const uint4*)(inb + ci * 8);
      int ir = ci >> 3, cc = ci & 7;
      int byte = ir * 128 + (((cc << 4)) ^ ((ir & 7) << 4));
      *(uint4*)((char*)As + byte) = v;
    }
  }

  // B fragments: wave owns nt = w (16 oc)
  half8 bfrag[9][2];
#pragma unroll
  for (int tap = 0; tap < 9; ++tap)
#pragma unroll
    for (int ch = 0; ch < 2; ++ch)
      bfrag[tap][ch] = *(const half8*)(
          w3T + (size_t)(tap * 64 + w * 16 + lc) * 64 + ch * 32 + q * 8);
  float b3v = b3[w * 16 + lc];

  __syncthreads();                              // the ONLY barrier

  half_t* ob = out + (size_t)li * 3136;         // k-order c*49+pos
#pragma unroll
  for (int tile = 0; tile < 4; ++tile) {
    int row16 = tile * 16 + lc;
    int orow = row16 < 49 ? row16 : 48;         // clamp dead rows
    int oy = orow / 7, ox = orow - oy * 7;
    f32x4 acc = (f32x4){0.f, 0.f, 0.f, 0.f};
#pragma unroll
    for (int tap = 0; tap < 9; ++tap) {
      int ky = tap / 3, kx = tap - ky * 3;
      int ir = (oy + ky) * 9 + ox + kx;
#pragma unroll
      for (int ch = 0; ch < 2; ++ch) {
        int byte = ir * 128 + (((ch << 6) | (q << 4)) ^ ((ir & 7) << 4));
        half8 af = *(const half8*)((const char*)As + byte);
        acc = __builtin_amdgcn_mfma_f32_16x16x32_f16(af, bfrag[tap][ch],
                                                     acc, 0, 0, 0);
      }
    }
    // C: pos=tile*16+q*4+r, col=w*16+lc; write out[col*49+pos]
#pragma unroll
    for (int r = 0; r < 4; ++r) {
      int pos = tile * 16 + q * 4 + r;
      if (pos < 49) {
        int col = w * 16 + lc;
        ob[(size_t)col * 49 + pos] = (half_t)fmaxf(acc[r] + b3v, 0.f);
      }
    }
  }
}

// ------- FC via MFMA, K-split x2 + dbuf single barrier ----------------------
// grid (8 n, 32 m, 2 kh). Each block: 49 K-steps over its 1568-half, writes
// RAW fp32 partial to h0/h1 (bias+relu folded into mid1's wfeat consumer).
// Dbuf hazard note: write at step s+1 targets the buffer last READ at s-1;
// the barrier at step s orders those reads before this write.
__global__ __launch_bounds__(256) void fc_mfma(
    const half_t* __restrict__ A, const half_t* __restrict__ Bt,
    float* __restrict__ h0, float* __restrict__ h1) {
  __shared__ __align__(16) half_t As[2][64 * 40];
  __shared__ __align__(16) half_t Bs[2][64 * 40];
  int tid = threadIdx.x;
  int m0 = blockIdx.y * 64, n0 = blockIdx.x * 64;
  int kh = blockIdx.z;
  int w = tid >> 6;
  int l = tid & 63;
  int lc = l & 15, q = l >> 4;
  int srow = tid >> 2, sseg = tid & 3;

  const half_t* aPtr = A + (size_t)(m0 + srow) * 3136 + kh * 1568 + sseg * 8;
  const half_t* bPtr = Bt + (size_t)(n0 + srow) * 3136 + kh * 1568 + sseg * 8;
  uint4 aReg = *(const uint4*)aPtr;
  uint4 bReg = *(const uint4*)bPtr;

  f32x4 acc[4];
#pragma unroll
  for (int t = 0; t < 4; ++t) acc[t] = (f32x4){0.f, 0.f, 0.f, 0.f};

  for (int s = 0; s < 49; ++s) {
    int cur = s & 1;
    *(uint4*)&As[cur][srow * 40 + sseg * 8] = aReg;
    *(uint4*)&Bs[cur][srow * 40 + sseg * 8] = bReg;
    __syncthreads();                         // the only barrier per step
    if (s < 48) {                            // prefetch overlaps MFMA below
      aReg = *(const uint4*)(aPtr + (s + 1) * 32);
      bReg = *(const uint4*)(bPtr + (s + 1) * 32);
    }
    half8 af = *(const half8*)&As[cur][(w * 16 + lc) * 40 + q * 8];
#pragma unroll
    for (int t = 0; t < 4; ++t) {
      half8 bf = *(const half8*)&Bs[cur][(t * 16 + lc) * 40 + q * 8];
      acc[t] = __builtin_amdgcn_mfma_f32_16x16x32_f16(af, bf, acc[t], 0, 0, 0);
    }
  }
  float* H = kh ? h1 : h0;
#pragma unroll
  for (int t = 0; t < 4; ++t) {
#pragma unroll
    for (int r = 0; r < 4; ++r) {
      int row = m0 + w * 16 + q * 4 + r;
      int col = n0 + t * 16 + lc;
      H[(size_t)row * 512 + col] = acc[t][r];
    }
  }
}

// ---------------- mid1: wfeat + posfeat + y0 (independent; one launch) ------
__global__ __launch_bounds__(256) void mid1_kernel(
    const float* __restrict__ h0, const float* __restrict__ h1,
    const float* __restrict__ bfc, const float* __restrict__ Ww,
    const float* __restrict__ bw, float* __restrict__ wf,
    const int* __restrict__ pos, const float* __restrict__ wp1,
    const float* __restrict__ bp1, const float* __restrict__ wp2,
    const float* __restrict__ bp2, float* __restrict__ pf,
    const float* __restrict__ s0, const float* __restrict__ wpo1,
    const float* __restrict__ wv1, float* __restrict__ y0) {
  __shared__ float red[128];
  int bx = blockIdx.x;
  if (bx < 256) {
    // ---- wfeat = relu(h0+h1+bfc) @ Ww + bw : [2048,512]@[512,32] ----
    int g = bx * 256 + threadIdx.x;
    int row = g >> 5, oc = g & 31;
    float acc = bw[oc];
    const float* hr0 = h0 + (size_t)row * 512;
    const float* hr1 = h1 + (size_t)row * 512;
#pragma unroll 8
    for (int k = 0; k < 512; ++k)
      acc += fmaxf(hr0[k] + hr1[k] + bfc[k], 0.f) * Ww[k * 32 + oc];
    wf[g] = acc;
    return;
  }
  if (bx < 768) {
    // ---- posfeat: one-hot MLP, one wave per row ----
    int row = ((bx - 256) * 256 + threadIdx.x) >> 6;  // 2048
    int l = threadIdx.x & 63;
    int p0 = pos[row * 2], p1 = pos[row * 2 + 1];
    float t1 = fmaxf(wp1[p0 * 64 + l] + wp1[(16 + p1) * 64 + l] + bp1[l], 0.f);
    float acc = bp2[l];
#pragma unroll
    for (int k = 0; k < 64; ++k) acc += __shfl(t1, k) * wp2[k * 64 + l];
    pf[row * 64 + l] = acc;
    return;
  }
  // ---- y0 = state0 @ [wpo1|wv1] : grid (b*32+kc), thread (kh2 x n128) ----
  int g = bx - 768;                                // 0..2047
  int b = g >> 5, kc = g & 31;                     // kc: 256-k chunk
  int n = threadIdx.x & 127, kh = threadIdx.x >> 7;
  const float* W = (n < 64) ? (wpo1 + n) : (wv1 + (n - 64));
  int k0 = kc * 256 + kh * 128;
  const float* s = s0 + (size_t)b * 8192 + k0;
  float acc = 0.f;
#pragma unroll 8
  for (int j = 0; j < 128; ++j) acc += s[j] * W[(size_t)(k0 + j) * 64];
  if (kh) red[n] = acc;
  __syncthreads();
  if (!kh) atomicAdd(y0 + b * 128 + n, acc + red[n]);
}

// ---------------- mid2: delta (parallel recurrence input) + final state -----
// delta[row][n] = sum_c wf[row][c] * W_n[(c*256+off_row)*64]  (coalesced 512B)
__global__ __launch_bounds__(256) void mid2_kernel(
    const int* __restrict__ pos, const float* __restrict__ wf,
    const float* __restrict__ wpo1, const float* __restrict__ wv1,
    float* __restrict__ delta, const float* __restrict__ s0,
    const float* __restrict__ done, float* __restrict__ out_state) {
  int bx = blockIdx.x;
  if (bx < 1024) {
    // ---- delta: 2 rows per block ----
    int row = bx * 2 + (threadIdx.x >> 7);
    int n = threadIdx.x & 127;
    const float* W = (n < 64) ? (wpo1 + n) : (wv1 + (n - 64));
    int off = pos[row * 2] * 16 + pos[row * 2 + 1];
    const float* wfr = wf + row * 32;
    float d = 0.f;
#pragma unroll
    for (int c = 0; c < 32; ++c) d += wfr[c] * W[(size_t)(c * 256 + off) * 64];
    delta[(size_t)row * 128 + n] = d;
    return;
  }
  // ---- final map state (output 2) ----
  int b = bx - 1024, tid = threadIdx.x;       // tid = spatial offset 0..255
  float s[32];
#pragma unroll
  for (int c = 0; c < 32; ++c) s[c] = s0[(size_t)b * 8192 + c * 256 + tid];
  for (int t = 0; t < TT; ++t) {
    int row = t * BB + b;
    float mask = 1.f - done[row];
    int off = pos[row * 2] * 16 + pos[row * 2 + 1];
#pragma unroll
    for (int c = 0; c < 32; ++c) s[c] *= mask;
    if (tid == off) {
#pragma unroll
      for (int c = 0; c < 32; ++c) s[c] += wf[row * 32 + c];
    }
  }
#pragma unroll
  for (int c = 0; c < 32; ++c) out_state[(size_t)b * 8192 + c * 256 + tid] = s[c];
}

// ---------------- scan: y = y*mask + delta (trivial recurrence) -------------
__global__ __launch_bounds__(128) void scan_kernel(
    const float* __restrict__ y0, const float* __restrict__ done,
    const float* __restrict__ delta, float* __restrict__ ys) {
  int b = blockIdx.x;
  int n = threadIdx.x;                      // 0..127
  float y = y0[b * 128 + n];
  for (int t = 0; t < TT; ++t) {
    int row = t * BB + b;
    y = y * (1.f - done[row]) + delta[(size_t)row * 128 + n];
    ys[(size_t)row * 128 + n] = y;
  }
}

// ---------------- heads: + pos-part of W1, ReLU, second layers ----------------
__global__ __launch_bounds__(256) void head_kernel(
    const float* __restrict__ ys, const float* __restrict__ pf,
    const float* __restrict__ wpo1, const float* __restrict__ wv1,
    const float* __restrict__ bpo1, const float* __restrict__ bv1,
    const float* __restrict__ wpo2, const float* __restrict__ bpo2,
    const float* __restrict__ wv2, const float* __restrict__ bv2,
    float* __restrict__ logits, float* __restrict__ vout) {
  int row = (blockIdx.x * 256 + threadIdx.x) >> 6;  // one wave per row
  int l = threadIdx.x & 63;
  float pfv = pf[row * 64 + l];
  float accp = bpo1[l] + ys[(size_t)row * 128 + l];
  float accv = bv1[l] + ys[(size_t)row * 128 + 64 + l];
#pragma unroll
  for (int k = 0; k < 64; ++k) {
    float pk = __shfl(pfv, k);
    accp += pk * wpo1[(size_t)(8192 + k) * 64 + l];
    accv += pk * wv1[(size_t)(8192 + k) * 64 + l];
  }
  float rp = fmaxf(accp, 0.f), rv = fmaxf(accv, 0.f);
#pragma unroll
  for (int a = 0; a < 5; ++a) {
    float pa = rp * wpo2[l * 5 + a];
#pragma unroll
    for (int m = 32; m >= 1; m >>= 1) pa += __shfl_xor(pa, m);
    if (l == 0) logits[row * 5 + a] = pa + bpo2[a];
  }
  float pv = rv * wv2[l];
#pragma unroll
  for (int m = 32; m >= 1; m >>= 1) pv += __shfl_xor(pv, m);
  if (l == 0) vout[row] = pv + bv2[0];
}

extern "C" void kernel_launch(void* const* d_in, const int* in_sizes, int n_in,
                              void* d_out, int out_size, void* d_ws, size_t ws_size,
                              hipStream_t stream) {
  const float* image = (const float*)d_in[0];
  const float* done = (const float*)d_in[1];
  const float* state0 = (const float*)d_in[2];
  const int* position = (const int*)d_in[3];
  const float* w1 = (const float*)d_in[4];
  const float* b1 = (const float*)d_in[5];
  const float* w2 = (const float*)d_in[6];
  const float* b2 = (const float*)d_in[7];
  const float* w3 = (const float*)d_in[8];
  const float* b3 = (const float*)d_in[9];
  const float* wfc = (const float*)d_in[10];
  const float* bfc = (const float*)d_in[11];
  const float* Ww = (const float*)d_in[12];
  const float* bw = (const float*)d_in[13];
  const float* wp1 = (const float*)d_in[14];
  const float* bp1 = (const float*)d_in[15];
  const float* wp2 = (const float*)d_in[16];
  const float* bp2 = (const float*)d_in[17];
  const float* wpo1 = (const float*)d_in[18];
  const float* bpo1 = (const float*)d_in[19];
  const float* wpo2 = (const float*)d_in[20];
  const float* bpo2 = (const float*)d_in[21];
  const float* wv1 = (const float*)d_in[22];
  const float* bv1 = (const float*)d_in[23];
  const float* wv2 = (const float*)d_in[24];
  const float* bv2 = (const float*)d_in[25];

  float* ws = (float*)d_ws;
  half_t* w1p = (half_t*)(ws + OFF_W1T);
  half_t* w2T = (half_t*)(ws + OFF_W2T);
  half_t* w3T = (half_t*)(ws + OFF_W3T);
  float* wf = ws + OFF_WF;
  float* pfb = ws + OFF_PF;
  float* y0 = ws + OFF_Y0;
  float* ysb = ws + OFF_YS;
  float* h0b = ws + OFF_H;
  float* h1b = ws + OFF_C2;           // reuses dead c2b space (post-conv3)
  float* deltab = ws + OFF_DELTA;
  half_t* wfcT = (half_t*)(ws + OFF_WFCT);
  half_t* c3b = (half_t*)(ws + OFF_C3);
  half_t* c2b = (half_t*)(ws + OFF_C2);
  half_t* c1b = (half_t*)(ws + OFF_C1);

  float* out = (float*)d_out;
  float* out_logits = out;            // [2048,5]
  float* out_v = out + 10240;         // [2048,1]
  float* out_state = out + 12288;     // [64,32,16,16]

  // Tier by ws_size (floats): A: CS=2048 no chunk, 97.0 MB;
  //                           B: CS=1024, 70.8 MB; C: CS=512, 57.7 MB.
  int CS;
  if (ws_size >= (size_t)24248320 * 4) CS = 2048;
  else if (ws_size >= (size_t)17694720 * 4) CS = 1024;
  else CS = 512;
  int nc = TBR / CS;

  hipMemsetAsync(y0, 0, 8192 * sizeof(float), stream);
  prep_all<<<1872, 256, 0, stream>>>(w1, w2, w3, w1p, w2T, w3T, wfc, wfcT);

  for (int c = 0; c < nc; ++c) {
    int n0 = c * CS;
    conv1_mfma<<<CS, 256, 0, stream>>>(image, w1p, b1, c1b, n0);
    conv2_mfma<<<CS, 256, 0, stream>>>(c1b, w2T, b2, c2b, n0);
  }
  conv3_mfma<<<TBR, 256, 0, stream>>>(c2b, w3T, b3, c3b);
  fc_mfma<<<dim3(8, 32, 2), 256, 0, stream>>>(c3b, wfcT, h0b, h1b);
  mid1_kernel<<<2816, 256, 0, stream>>>(h0b, h1b, bfc, Ww, bw, wf, position,
                                        wp1, bp1, wp2, bp2, pfb, state0,
                                        wpo1, wv1, y0);
  mid2_kernel<<<1088, 256, 0, stream>>>(position, wf, wpo1, wv1, deltab,
                                        state0, done, out_state);
  scan_kernel<<<64, 128, 0, stream>>>(y0, done, deltab, ysb);
  head_kernel<<<512, 256, 0, stream>>>(ysb, pfb, wpo1, wv1, bpo1, bv1,
                                       wpo2, bpo2, wv2, bv2, out_logits, out_v);
}